// Round 1
// baseline (974.609 us; speedup 1.0000x reference)
//
#include <hip/hip_runtime.h>
#include <math.h>

#define B_ 2
#define N_ 6400
#define E_ 256
#define C_ 6
#define L_ 4

// Level geometry (H, W), flattened per-channel offsets, total pixels/channel
__device__ __host__ constexpr int HWH[4] = {64, 32, 16, 8};
__device__ __host__ constexpr int HWW[4] = {176, 88, 44, 22};
__device__ __host__ constexpr int LOFF[4] = {0, 11264, 14080, 14784};
#define HWT 14960

// ---------------------------------------------------------------------------
// Kernel 1: per-point prep.
// Computes attention softmax weights, camera projections, and per-(n,c,l)
// "slot" weights: 4 weights s.t. sum_j w_j * feat[base + dj] reproduces the
// reference bilinear-with-zero-padding exactly (border clamping folded in).
// ---------------------------------------------------------------------------
__global__ __launch_bounds__(256) void prep_kernel(
    const float* __restrict__ inst, const float* __restrict__ anchor,
    const float* __restrict__ proj, const float* __restrict__ attn_w,
    const float* __restrict__ attn_b,
    float4* __restrict__ meta_w, int* __restrict__ meta_b)
{
    __shared__ float AWT[256 * 24];   // attn_w transposed [k][j]
    __shared__ float ts[256 * 33];    // inst tile [point][k-chunk], padded

    const int tid = threadIdx.x;

    // Stage attn_w transposed into LDS (coalesced read over k)
    for (int idx = tid; idx < 24 * 256; idx += 256) {
        int j = idx >> 8, k = idx & 255;
        AWT[k * 24 + j] = attn_w[idx];
    }
    __syncthreads();

    const int pt0 = blockIdx.x * 256;

    float acc[24];
#pragma unroll
    for (int j = 0; j < 24; j++) acc[j] = attn_b[j];

    // 24 dot products of length 256, k-chunked through LDS for coalescing
    for (int k0 = 0; k0 < 256; k0 += 32) {
#pragma unroll
        for (int r = 0; r < 32; r++) {
            int lin = r * 256 + tid;
            int p = lin >> 5, kk = lin & 31;
            ts[p * 33 + kk] = inst[(size_t)(pt0 + p) * 256 + k0 + kk];
        }
        __syncthreads();
#pragma unroll
        for (int kk = 0; kk < 32; kk++) {
            float v = ts[tid * 33 + kk];
            const float* aw = &AWT[(k0 + kk) * 24];
#pragma unroll
            for (int j = 0; j < 24; j++) acc[j] += v * aw[j];
        }
        __syncthreads();
    }

    const int pt = pt0 + tid;
    const int b = pt / N_;   // uniform per block (6400 % 256 == 0)
    const int n = pt - b * N_;

    // softmax over levels within each cam
    float attn[24];
#pragma unroll
    for (int c = 0; c < C_; c++) {
        float m = fmaxf(fmaxf(acc[c * 4], acc[c * 4 + 1]),
                        fmaxf(acc[c * 4 + 2], acc[c * 4 + 3]));
        float s = 0.f;
#pragma unroll
        for (int l = 0; l < L_; l++) {
            float e = expf(acc[c * 4 + l] - m);
            attn[c * 4 + l] = e;
            s += e;
        }
        float r = 1.f / s;
#pragma unroll
        for (int l = 0; l < L_; l++) attn[c * 4 + l] *= r;
    }

    // anchor -> sigmoid -> world coords
    float ax = anchor[(size_t)pt * 11 + 0];
    float ay = anchor[(size_t)pt * 11 + 1];
    float az = anchor[(size_t)pt * 11 + 2];
    float wxp = (1.f / (1.f + expf(-ax))) * 102.4f - 51.2f;
    float wyp = (1.f / (1.f + expf(-ay))) * 102.4f - 51.2f;
    float wzp = (1.f / (1.f + expf(-az))) * 8.f - 5.f;

#pragma unroll
    for (int c = 0; c < C_; c++) {
        const float* P = &proj[(size_t)(b * C_ + c) * 16];
        float cx = P[0] * wxp + P[1] * wyp + P[2] * wzp + P[3];
        float cy = P[4] * wxp + P[5] * wyp + P[6] * wzp + P[7];
        float cz = P[8] * wxp + P[9] * wyp + P[10] * wzp + P[11];
        float d = fmaxf(cz, 1e-4f);
        float u = cx / d, v = cy / d;

        float x0f = floorf(u), y0f = floorf(v);
        float fx1 = u - x0f, fy1 = v - y0f;
        float fx0 = 1.f - fx1, fy0 = 1.f - fy1;

#pragma unroll
        for (int l = 0; l < L_; l++) {
            const int W = HWW[l], H = HWH[l];
            // x-side slot weights (slots read bx, bx+1)
            float ax0, ax1; int bx;
            int ix = (int)fminf(fmaxf(x0f, -2.f), (float)W);
            if (ix <= -2 || ix >= W)      { ax0 = 0.f;  ax1 = 0.f;  bx = 0; }
            else if (ix == -1)            { ax0 = fx1;  ax1 = 0.f;  bx = 0; }
            else if (ix == W - 1)         { ax0 = 0.f;  ax1 = fx0;  bx = W - 2; }
            else                          { ax0 = fx0;  ax1 = fx1;  bx = ix; }
            // y-side
            float ay0, ay1; int by;
            int iy = (int)fminf(fmaxf(y0f, -2.f), (float)H);
            if (iy <= -2 || iy >= H)      { ay0 = 0.f;  ay1 = 0.f;  by = 0; }
            else if (iy == -1)            { ay0 = fy1;  ay1 = 0.f;  by = 0; }
            else if (iy == H - 1)         { ay0 = 0.f;  ay1 = fy0;  by = H - 2; }
            else                          { ay0 = fy0;  ay1 = fy1;  by = iy; }

            float a = attn[c * 4 + l];
            float4 w4 = make_float4(a * ay0 * ax0, a * ay0 * ax1,
                                    a * ay1 * ax0, a * ay1 * ax1);
            int midx = ((b * C_ + c) * L_ + l) * N_ + n;
            meta_w[midx] = w4;
            meta_b[midx] = by * W + bx;
        }
    }
}

// ---------------------------------------------------------------------------
// Kernel 2: gather. Block = (b, cam, 2-channel slice). Stage both channel
// planes (all 4 levels) interleaved [pix][ch] into LDS, then loop points,
// gather 2x2 window per level with precomputed slot weights, atomicAdd
// into agg (= d_out, zeroed).
// ---------------------------------------------------------------------------
__global__ __launch_bounds__(512) void gather_kernel(
    const float* __restrict__ f0, const float* __restrict__ f1,
    const float* __restrict__ f2, const float* __restrict__ f3,
    const float4* __restrict__ meta_w, const int* __restrict__ meta_b,
    float* __restrict__ agg)
{
    __shared__ float lds[2 * HWT];   // interleaved [pixel][channel], 119680 B

    const int tid = threadIdx.x;
    const int bid = blockIdx.x;
    const int ech = bid & 127;           // E/2 = 128 slices
    const int c = (bid >> 7) % C_;
    const int b = bid / (128 * C_);
    const int e0 = ech * 2;

    const float* fs[4] = {f0, f1, f2, f3};

#pragma unroll
    for (int l = 0; l < L_; l++) {
        const int HW = HWH[l] * HWW[l];
        const float* srcA = fs[l] + (size_t)((b * C_ + c) * E_ + e0) * HW;
        const float* srcB = srcA + HW;
        const int half = HW >> 1;
        for (int q = tid; q < half; q += 512) {
            int p = q * 2;
            float2 a = *(const float2*)(srcA + p);
            float2 bb = *(const float2*)(srcB + p);
            float4 w;
            w.x = a.x; w.y = bb.x; w.z = a.y; w.w = bb.y;
            *(float4*)(&lds[(LOFF[l] + p) * 2]) = w;
        }
    }
    __syncthreads();

    float* aggb = agg + (size_t)b * N_ * E_ + e0;
    const int mbase = (b * C_ + c) * L_;

    for (int n = tid; n < N_; n += 512) {
        float4 w[4]; int bs[4];
#pragma unroll
        for (int l = 0; l < L_; l++) {
            int midx = (mbase + l) * N_ + n;
            w[l] = meta_w[midx];
            bs[l] = meta_b[midx];
        }
        float acc0 = 0.f, acc1 = 0.f;
#pragma unroll
        for (int l = 0; l < L_; l++) {
            if (w[l].x == 0.f && w[l].y == 0.f && w[l].z == 0.f && w[l].w == 0.f)
                continue;
            const int W2 = HWW[l] * 2;
            const float* p = &lds[(LOFF[l] + bs[l]) * 2];
            acc0 += w[l].x * p[0] + w[l].y * p[2] + w[l].z * p[W2]     + w[l].w * p[W2 + 2];
            acc1 += w[l].x * p[1] + w[l].y * p[3] + w[l].z * p[W2 + 1] + w[l].w * p[W2 + 3];
        }
        if (acc0 != 0.f || acc1 != 0.f) {
            atomicAdd(&aggb[(size_t)n * E_ + 0], acc0);
            atomicAdd(&aggb[(size_t)n * E_ + 1], acc1);
        }
    }
}

// ---------------------------------------------------------------------------
// Kernel 3: fused epilogue, in place on d_out:
//   tmp = agg @ vp_w^T + vp_b + inst ;  out = tmp @ op_w^T + op_b
// 32 points/block, 256 threads, thread = 4p x 8e register block.
// ---------------------------------------------------------------------------
#define PT 32
#define SAS 260   // sA row stride (floats)

__global__ __launch_bounds__(256) void gemm_kernel(
    const float* __restrict__ inst,
    const float* __restrict__ vp_w, const float* __restrict__ vp_b,
    const float* __restrict__ op_w, const float* __restrict__ op_b,
    float* __restrict__ io)
{
    __shared__ float sA[PT * SAS];    // 33280 B  (agg tile, then tmp tile)
    __shared__ float wS[256 * 33];    // 33792 B  (weight k-chunk, transp-padded)

    const int tid = threadIdx.x;
    const int eg = tid & 31;
    const int pg = tid >> 5;
    const int p0 = blockIdx.x * PT;

    // stage agg tile [32][256]
#pragma unroll
    for (int r = 0; r < PT; r++)
        sA[r * SAS + tid] = io[(size_t)(p0 + r) * E_ + tid];
    __syncthreads();

    float acc[4][8];
#pragma unroll
    for (int j = 0; j < 4; j++)
#pragma unroll
        for (int i = 0; i < 8; i++) acc[j][i] = 0.f;

    // ---- GEMM1: tmp = agg @ vp_w^T ----
    for (int k0 = 0; k0 < 256; k0 += 32) {
        __syncthreads();
#pragma unroll
        for (int r = 0; r < 32; r++) {
            int lin = r * 256 + tid;
            int e = lin >> 5, kk = lin & 31;
            wS[e * 33 + kk] = vp_w[(size_t)e * 256 + k0 + kk];
        }
        __syncthreads();
#pragma unroll
        for (int kk = 0; kk < 32; kk++) {
            float av[4], wv[8];
#pragma unroll
            for (int j = 0; j < 4; j++) av[j] = sA[(pg * 4 + j) * SAS + k0 + kk];
#pragma unroll
            for (int i = 0; i < 8; i++) wv[i] = wS[(eg + 32 * i) * 33 + kk];
#pragma unroll
            for (int j = 0; j < 4; j++)
#pragma unroll
                for (int i = 0; i < 8; i++) acc[j][i] += av[j] * wv[i];
        }
    }

    // tmp += vp_b + inst ; store into sA (reuse); reset acc
    __syncthreads();
#pragma unroll
    for (int j = 0; j < 4; j++) {
        int p = pg * 4 + j;
#pragma unroll
        for (int i = 0; i < 8; i++) {
            int e = eg + 32 * i;
            float t = acc[j][i] + vp_b[e] + inst[(size_t)(p0 + p) * E_ + e];
            sA[p * SAS + e] = t;
            acc[j][i] = 0.f;
        }
    }

    // ---- GEMM2: out = tmp @ op_w^T ----
    for (int k0 = 0; k0 < 256; k0 += 32) {
        __syncthreads();
#pragma unroll
        for (int r = 0; r < 32; r++) {
            int lin = r * 256 + tid;
            int e = lin >> 5, kk = lin & 31;
            wS[e * 33 + kk] = op_w[(size_t)e * 256 + k0 + kk];
        }
        __syncthreads();
#pragma unroll
        for (int kk = 0; kk < 32; kk++) {
            float av[4], wv[8];
#pragma unroll
            for (int j = 0; j < 4; j++) av[j] = sA[(pg * 4 + j) * SAS + k0 + kk];
#pragma unroll
            for (int i = 0; i < 8; i++) wv[i] = wS[(eg + 32 * i) * 33 + kk];
#pragma unroll
            for (int j = 0; j < 4; j++)
#pragma unroll
                for (int i = 0; i < 8; i++) acc[j][i] += av[j] * wv[i];
        }
    }

#pragma unroll
    for (int j = 0; j < 4; j++) {
        int p = pg * 4 + j;
#pragma unroll
        for (int i = 0; i < 8; i++) {
            int e = eg + 32 * i;
            io[(size_t)(p0 + p) * E_ + e] = acc[j][i] + op_b[e];
        }
    }
}

// ---------------------------------------------------------------------------
extern "C" void kernel_launch(void* const* d_in, const int* in_sizes, int n_in,
                              void* d_out, int out_size, void* d_ws, size_t ws_size,
                              hipStream_t stream)
{
    const float* inst   = (const float*)d_in[0];
    const float* anchor = (const float*)d_in[1];
    const float* proj   = (const float*)d_in[2];
    const float* f0     = (const float*)d_in[3];
    const float* f1     = (const float*)d_in[4];
    const float* f2     = (const float*)d_in[5];
    const float* f3     = (const float*)d_in[6];
    const float* attn_w = (const float*)d_in[7];
    const float* attn_b = (const float*)d_in[8];
    const float* vp_w   = (const float*)d_in[9];
    const float* vp_b   = (const float*)d_in[10];
    const float* op_w   = (const float*)d_in[11];
    const float* op_b   = (const float*)d_in[12];
    float* out = (float*)d_out;

    // ws layout: meta_w (float4 per (b,c,l,n)) then meta_b (int per (b,c,l,n))
    float4* meta_w = (float4*)d_ws;
    int* meta_b = (int*)((char*)d_ws + (size_t)B_ * C_ * L_ * N_ * sizeof(float4));

    hipMemsetAsync(d_out, 0, (size_t)out_size * sizeof(float), stream);

    prep_kernel<<<(B_ * N_) / 256, 256, 0, stream>>>(
        inst, anchor, proj, attn_w, attn_b, meta_w, meta_b);

    gather_kernel<<<B_ * C_ * (E_ / 2), 512, 0, stream>>>(
        f0, f1, f2, f3, meta_w, meta_b, out);

    gemm_kernel<<<(B_ * N_) / PT, 256, 0, stream>>>(
        inst, vp_w, vp_b, op_w, op_b, out);
}

// Round 2
// 889.011 us; speedup vs baseline: 1.0963x; 1.0963x over previous
//
#include <hip/hip_runtime.h>
#include <hip/hip_fp16.h>
#include <math.h>

#define B_ 2
#define N_ 6400
#define E_ 256
#define C_ 6
#define L_ 4

// Level geometry (H, W), flattened per-channel offsets, total pixels/channel
__device__ __host__ constexpr int HWH[4] = {64, 32, 16, 8};
__device__ __host__ constexpr int HWW[4] = {176, 88, 44, 22};
__device__ __host__ constexpr int LOFF[4] = {0, 11264, 14080, 14784};
#define HWT 14960

struct __align__(8) H4 { __half2 lo, hi; };   // 4 fp16 channels of one pixel

// ---------------------------------------------------------------------------
// Kernel 1: per-point prep.
// attention softmax + projection + per-(n,c,l) slot weights (border clamp and
// zero-padding folded into the 4 weights; gather then reads an unconditional
// 2x2 window at a clamped base).
// meta layout: meta_w[(b*C+c)*N + n][l] : float4   (64 B per point, contiguous)
//              meta_b[(b*C+c)*N + n]    : int4     (base pixel per level)
// ---------------------------------------------------------------------------
__global__ __launch_bounds__(256) void prep_kernel(
    const float* __restrict__ inst, const float* __restrict__ anchor,
    const float* __restrict__ proj, const float* __restrict__ attn_w,
    const float* __restrict__ attn_b,
    float4* __restrict__ meta_w, int4* __restrict__ meta_b)
{
    __shared__ float AWT[256 * 24];   // attn_w transposed [k][j]
    __shared__ float ts[256 * 33];    // inst tile [point][k-chunk], padded

    const int tid = threadIdx.x;

    for (int idx = tid; idx < 24 * 256; idx += 256) {
        int j = idx >> 8, k = idx & 255;
        AWT[k * 24 + j] = attn_w[idx];
    }
    __syncthreads();

    const int pt0 = blockIdx.x * 256;

    float acc[24];
#pragma unroll
    for (int j = 0; j < 24; j++) acc[j] = attn_b[j];

    for (int k0 = 0; k0 < 256; k0 += 32) {
#pragma unroll
        for (int r = 0; r < 32; r++) {
            int lin = r * 256 + tid;
            int p = lin >> 5, kk = lin & 31;
            ts[p * 33 + kk] = inst[(size_t)(pt0 + p) * 256 + k0 + kk];
        }
        __syncthreads();
#pragma unroll
        for (int kk = 0; kk < 32; kk++) {
            float v = ts[tid * 33 + kk];
            const float* aw = &AWT[(k0 + kk) * 24];
#pragma unroll
            for (int j = 0; j < 24; j++) acc[j] += v * aw[j];
        }
        __syncthreads();
    }

    const int pt = pt0 + tid;
    const int b = pt / N_;   // uniform per block (6400 % 256 == 0)
    const int n = pt - b * N_;

    float attn[24];
#pragma unroll
    for (int c = 0; c < C_; c++) {
        float m = fmaxf(fmaxf(acc[c * 4], acc[c * 4 + 1]),
                        fmaxf(acc[c * 4 + 2], acc[c * 4 + 3]));
        float s = 0.f;
#pragma unroll
        for (int l = 0; l < L_; l++) {
            float e = expf(acc[c * 4 + l] - m);
            attn[c * 4 + l] = e;
            s += e;
        }
        float r = 1.f / s;
#pragma unroll
        for (int l = 0; l < L_; l++) attn[c * 4 + l] *= r;
    }

    float ax = anchor[(size_t)pt * 11 + 0];
    float ay = anchor[(size_t)pt * 11 + 1];
    float az = anchor[(size_t)pt * 11 + 2];
    float wxp = (1.f / (1.f + expf(-ax))) * 102.4f - 51.2f;
    float wyp = (1.f / (1.f + expf(-ay))) * 102.4f - 51.2f;
    float wzp = (1.f / (1.f + expf(-az))) * 8.f - 5.f;

#pragma unroll
    for (int c = 0; c < C_; c++) {
        const float* P = &proj[(size_t)(b * C_ + c) * 16];
        float cx = P[0] * wxp + P[1] * wyp + P[2] * wzp + P[3];
        float cy = P[4] * wxp + P[5] * wyp + P[6] * wzp + P[7];
        float cz = P[8] * wxp + P[9] * wyp + P[10] * wzp + P[11];
        float d = fmaxf(cz, 1e-4f);
        float u = cx / d, v = cy / d;

        float x0f = floorf(u), y0f = floorf(v);
        float fx1 = u - x0f, fy1 = v - y0f;
        float fx0 = 1.f - fx1, fy0 = 1.f - fy1;

        float4 wl[4]; int bsx[4];
#pragma unroll
        for (int l = 0; l < L_; l++) {
            const int W = HWW[l], H = HWH[l];
            float ax0, ax1; int bx;
            int ix = (int)fminf(fmaxf(x0f, -2.f), (float)W);
            if (ix <= -2 || ix >= W)      { ax0 = 0.f;  ax1 = 0.f;  bx = 0; }
            else if (ix == -1)            { ax0 = fx1;  ax1 = 0.f;  bx = 0; }
            else if (ix == W - 1)         { ax0 = 0.f;  ax1 = fx0;  bx = W - 2; }
            else                          { ax0 = fx0;  ax1 = fx1;  bx = ix; }
            float ay0, ay1; int by;
            int iy = (int)fminf(fmaxf(y0f, -2.f), (float)H);
            if (iy <= -2 || iy >= H)      { ay0 = 0.f;  ay1 = 0.f;  by = 0; }
            else if (iy == -1)            { ay0 = fy1;  ay1 = 0.f;  by = 0; }
            else if (iy == H - 1)         { ay0 = 0.f;  ay1 = fy0;  by = H - 2; }
            else                          { ay0 = fy0;  ay1 = fy1;  by = iy; }

            float a = attn[c * 4 + l];
            wl[l] = make_float4(a * ay0 * ax0, a * ay0 * ax1,
                                a * ay1 * ax0, a * ay1 * ax1);
            bsx[l] = by * W + bx;
        }
        size_t mi = (size_t)(b * C_ + c) * N_ + n;
        float4* mw = meta_w + mi * 4;
        mw[0] = wl[0]; mw[1] = wl[1]; mw[2] = wl[2]; mw[3] = wl[3];
        meta_b[mi] = make_int4(bsx[0], bsx[1], bsx[2], bsx[3]);
    }
}

// ---------------------------------------------------------------------------
// Kernel 2: gather. Block = (b, cam, 4-channel slice). Stage 4 channel planes
// (all levels) as fp16 interleaved [pixel][4ch] into LDS (119.7 KB), then
// pipeline over points: 5 vector meta loads -> 16 ds_read_b64 gathers ->
// 4 atomicAdds into agg (= d_out, zeroed).
// ---------------------------------------------------------------------------
__global__ __launch_bounds__(1024) void gather_kernel(
    const float* __restrict__ f0, const float* __restrict__ f1,
    const float* __restrict__ f2, const float* __restrict__ f3,
    const float4* __restrict__ meta_w, const int4* __restrict__ meta_b,
    float* __restrict__ agg)
{
    __shared__ H4 lds4[HWT];   // 119680 B

    const int tid = threadIdx.x;
    const int bid = blockIdx.x;
    const int slice = bid & 63;          // E/4 = 64 slices
    const int c = (bid >> 6) % C_;
    const int b = bid / (64 * C_);
    const int e0 = slice * 4;

    const float* fs[4] = {f0, f1, f2, f3};

#pragma unroll
    for (int l = 0; l < L_; l++) {
        const int HW = HWH[l] * HWW[l];
        const float* s0 = fs[l] + (size_t)((b * C_ + c) * E_ + e0) * HW;
        const float* s1 = s0 + HW;
        const float* s2 = s1 + HW;
        const float* s3 = s2 + HW;
        const int half = HW >> 1;
        for (int q = tid; q < half; q += 1024) {
            int p = q * 2;
            float2 v0 = *(const float2*)(s0 + p);
            float2 v1 = *(const float2*)(s1 + p);
            float2 v2 = *(const float2*)(s2 + p);
            float2 v3 = *(const float2*)(s3 + p);
            union { uint4 u; __half2 h[4]; } pk;
            pk.h[0] = __floats2half2_rn(v0.x, v1.x);   // pixel p   ch0,ch1
            pk.h[1] = __floats2half2_rn(v2.x, v3.x);   // pixel p   ch2,ch3
            pk.h[2] = __floats2half2_rn(v0.y, v1.y);   // pixel p+1 ch0,ch1
            pk.h[3] = __floats2half2_rn(v2.y, v3.y);   // pixel p+1 ch2,ch3
            *(uint4*)&lds4[LOFF[l] + p] = pk.u;
        }
    }
    __syncthreads();

    float* aggb = agg + (size_t)b * N_ * E_ + e0;
    const size_t mbase = (size_t)(b * C_ + c) * N_;
    const float4* mwp = meta_w + mbase * 4;
    const int4* mbp = meta_b + mbase;

    int n = tid;
    float4 w0, w1, w2, w3; int4 px;
    {
        const float4* m = mwp + (size_t)n * 4;
        w0 = m[0]; w1 = m[1]; w2 = m[2]; w3 = m[3];
        px = mbp[n];
    }

    while (n < N_) {
        int nn = n + 1024;
        float4 u0, u1, u2, u3; int4 px2;
        if (nn < N_) {
            const float4* m = mwp + (size_t)nn * 4;
            u0 = m[0]; u1 = m[1]; u2 = m[2]; u3 = m[3];
            px2 = mbp[nn];
        }

        float a0 = 0.f, a1 = 0.f, a2 = 0.f, a3 = 0.f;
        const float4 ws[4] = {w0, w1, w2, w3};
        const int pxs[4] = {px.x, px.y, px.z, px.w};
#pragma unroll
        for (int l = 0; l < L_; l++) {
            float4 w = ws[l];
            if (w.x != 0.f || w.y != 0.f || w.z != 0.f || w.w != 0.f) {
                const int W = HWW[l];
                const int base = LOFF[l] + pxs[l];
                H4 c00 = lds4[base];
                H4 c01 = lds4[base + 1];
                H4 c10 = lds4[base + W];
                H4 c11 = lds4[base + W + 1];
                float2 f00a = __half22float2(c00.lo), f00b = __half22float2(c00.hi);
                float2 f01a = __half22float2(c01.lo), f01b = __half22float2(c01.hi);
                float2 f10a = __half22float2(c10.lo), f10b = __half22float2(c10.hi);
                float2 f11a = __half22float2(c11.lo), f11b = __half22float2(c11.hi);
                a0 += w.x * f00a.x + w.y * f01a.x + w.z * f10a.x + w.w * f11a.x;
                a1 += w.x * f00a.y + w.y * f01a.y + w.z * f10a.y + w.w * f11a.y;
                a2 += w.x * f00b.x + w.y * f01b.x + w.z * f10b.x + w.w * f11b.x;
                a3 += w.x * f00b.y + w.y * f01b.y + w.z * f10b.y + w.w * f11b.y;
            }
        }
        if (a0 != 0.f || a1 != 0.f || a2 != 0.f || a3 != 0.f) {
            float* dst = aggb + (size_t)n * E_;
            atomicAdd(dst + 0, a0);
            atomicAdd(dst + 1, a1);
            atomicAdd(dst + 2, a2);
            atomicAdd(dst + 3, a3);
        }

        n = nn;
        w0 = u0; w1 = u1; w2 = u2; w3 = u3; px = px2;
    }
}

// ---------------------------------------------------------------------------
// Kernel 3: fused epilogue, in place on d_out:
//   tmp = agg @ vp_w^T + vp_b + inst ;  out = tmp @ op_w^T + op_b
// 32 points/block, 256 threads, thread = 4p x 8e register block,
// float4 (b128) LDS reads over the k dimension.
// ---------------------------------------------------------------------------
#define PT 32
#define SAS 264   // sA row stride (floats), 16B-aligned rows
#define WSS 36    // wS row stride (floats), 16B-aligned rows

__global__ __launch_bounds__(256) void gemm_kernel(
    const float* __restrict__ inst,
    const float* __restrict__ vp_w, const float* __restrict__ vp_b,
    const float* __restrict__ op_w, const float* __restrict__ op_b,
    float* __restrict__ io)
{
    __shared__ float sA[PT * SAS];    // 33792 B
    __shared__ float wS[256 * WSS];   // 36864 B

    const int tid = threadIdx.x;
    const int eg = tid & 31;
    const int pg = tid >> 5;
    const int p0 = blockIdx.x * PT;

#pragma unroll
    for (int r = 0; r < PT; r++)
        sA[r * SAS + tid] = io[(size_t)(p0 + r) * E_ + tid];
    __syncthreads();

    float acc[4][8];
#pragma unroll
    for (int j = 0; j < 4; j++)
#pragma unroll
        for (int i = 0; i < 8; i++) acc[j][i] = 0.f;

    // ---- GEMM1: tmp = agg @ vp_w^T ----
    for (int k0 = 0; k0 < 256; k0 += 32) {
        __syncthreads();
#pragma unroll
        for (int r = 0; r < 32; r++) {
            int lin = r * 256 + tid;
            int e = lin >> 5, kk = lin & 31;
            wS[e * WSS + kk] = vp_w[(size_t)e * 256 + k0 + kk];
        }
        __syncthreads();
#pragma unroll
        for (int kk = 0; kk < 32; kk += 4) {
            float4 wv4[8], av4[4];
#pragma unroll
            for (int i = 0; i < 8; i++)
                wv4[i] = *(const float4*)&wS[(eg + 32 * i) * WSS + kk];
#pragma unroll
            for (int j = 0; j < 4; j++)
                av4[j] = *(const float4*)&sA[(pg * 4 + j) * SAS + k0 + kk];
#pragma unroll
            for (int j = 0; j < 4; j++)
#pragma unroll
                for (int i = 0; i < 8; i++)
                    acc[j][i] += av4[j].x * wv4[i].x + av4[j].y * wv4[i].y
                               + av4[j].z * wv4[i].z + av4[j].w * wv4[i].w;
        }
    }

    // tmp += vp_b + inst ; store into sA (reuse); reset acc
    __syncthreads();
#pragma unroll
    for (int j = 0; j < 4; j++) {
        int p = pg * 4 + j;
#pragma unroll
        for (int i = 0; i < 8; i++) {
            int e = eg + 32 * i;
            float t = acc[j][i] + vp_b[e] + inst[(size_t)(p0 + p) * E_ + e];
            sA[p * SAS + e] = t;
            acc[j][i] = 0.f;
        }
    }

    // ---- GEMM2: out = tmp @ op_w^T ----
    for (int k0 = 0; k0 < 256; k0 += 32) {
        __syncthreads();
#pragma unroll
        for (int r = 0; r < 32; r++) {
            int lin = r * 256 + tid;
            int e = lin >> 5, kk = lin & 31;
            wS[e * WSS + kk] = op_w[(size_t)e * 256 + k0 + kk];
        }
        __syncthreads();
#pragma unroll
        for (int kk = 0; kk < 32; kk += 4) {
            float4 wv4[8], av4[4];
#pragma unroll
            for (int i = 0; i < 8; i++)
                wv4[i] = *(const float4*)&wS[(eg + 32 * i) * WSS + kk];
#pragma unroll
            for (int j = 0; j < 4; j++)
                av4[j] = *(const float4*)&sA[(pg * 4 + j) * SAS + k0 + kk];
#pragma unroll
            for (int j = 0; j < 4; j++)
#pragma unroll
                for (int i = 0; i < 8; i++)
                    acc[j][i] += av4[j].x * wv4[i].x + av4[j].y * wv4[i].y
                               + av4[j].z * wv4[i].z + av4[j].w * wv4[i].w;
        }
    }

#pragma unroll
    for (int j = 0; j < 4; j++) {
        int p = pg * 4 + j;
#pragma unroll
        for (int i = 0; i < 8; i++) {
            int e = eg + 32 * i;
            io[(size_t)(p0 + p) * E_ + e] = acc[j][i] + op_b[e];
        }
    }
}

// ---------------------------------------------------------------------------
extern "C" void kernel_launch(void* const* d_in, const int* in_sizes, int n_in,
                              void* d_out, int out_size, void* d_ws, size_t ws_size,
                              hipStream_t stream)
{
    const float* inst   = (const float*)d_in[0];
    const float* anchor = (const float*)d_in[1];
    const float* proj   = (const float*)d_in[2];
    const float* f0     = (const float*)d_in[3];
    const float* f1     = (const float*)d_in[4];
    const float* f2     = (const float*)d_in[5];
    const float* f3     = (const float*)d_in[6];
    const float* attn_w = (const float*)d_in[7];
    const float* attn_b = (const float*)d_in[8];
    const float* vp_w   = (const float*)d_in[9];
    const float* vp_b   = (const float*)d_in[10];
    const float* op_w   = (const float*)d_in[11];
    const float* op_b   = (const float*)d_in[12];
    float* out = (float*)d_out;

    // ws layout: meta_w [(b,c,n)][4] float4, then meta_b [(b,c,n)] int4
    float4* meta_w = (float4*)d_ws;
    int4* meta_b = (int4*)((char*)d_ws + (size_t)B_ * C_ * N_ * 4 * sizeof(float4));

    hipMemsetAsync(d_out, 0, (size_t)out_size * sizeof(float), stream);

    prep_kernel<<<(B_ * N_) / 256, 256, 0, stream>>>(
        inst, anchor, proj, attn_w, attn_b, meta_w, meta_b);

    gather_kernel<<<B_ * C_ * (E_ / 4), 1024, 0, stream>>>(
        f0, f1, f2, f3, meta_w, meta_b, out);

    gemm_kernel<<<(B_ * N_) / PT, 256, 0, stream>>>(
        inst, vp_w, vp_b, op_w, op_b, out);
}

// Round 3
// 455.671 us; speedup vs baseline: 2.1388x; 1.9510x over previous
//
#include <hip/hip_runtime.h>
#include <hip/hip_fp16.h>
#include <math.h>

#define B_ 2
#define N_ 6400
#define E_ 256
#define C_ 6
#define L_ 4
#define SL_ 64   // channel slices (E/4)

// Level geometry (H, W), flattened per-channel offsets, total pixels/channel
__device__ __host__ constexpr int HWH[4] = {64, 32, 16, 8};
__device__ __host__ constexpr int HWW[4] = {176, 88, 44, 22};
__device__ __host__ constexpr int LOFF[4] = {0, 11264, 14080, 14784};
#define HWT 14960

struct __align__(8) H4 { __half2 lo, hi; };   // 4 fp16 values

// ---------------------------------------------------------------------------
// Kernel 1: per-point prep.
// attention softmax + projection + per-(n,c,l) slot weights (border clamp and
// zero-padding folded into the 4 weights). Meta is fp16-compressed:
//   meta_w: uint4[mi*2+{0,1}]  = 16 half weights (4 per level)
//   meta_b: int4[mi]           = base pixel per level
// where mi = (b*C+c)*N + n.
// ---------------------------------------------------------------------------
__global__ __launch_bounds__(256) void prep_kernel(
    const float* __restrict__ inst, const float* __restrict__ anchor,
    const float* __restrict__ proj, const float* __restrict__ attn_w,
    const float* __restrict__ attn_b,
    uint4* __restrict__ meta_w, int4* __restrict__ meta_b)
{
    __shared__ float AWT[256 * 24];   // attn_w transposed [k][j]
    __shared__ float ts[256 * 33];    // inst tile [point][k-chunk], padded

    const int tid = threadIdx.x;

    for (int idx = tid; idx < 24 * 256; idx += 256) {
        int j = idx >> 8, k = idx & 255;
        AWT[k * 24 + j] = attn_w[idx];
    }
    __syncthreads();

    const int pt0 = blockIdx.x * 256;

    float acc[24];
#pragma unroll
    for (int j = 0; j < 24; j++) acc[j] = attn_b[j];

    for (int k0 = 0; k0 < 256; k0 += 32) {
#pragma unroll
        for (int r = 0; r < 32; r++) {
            int lin = r * 256 + tid;
            int p = lin >> 5, kk = lin & 31;
            ts[p * 33 + kk] = inst[(size_t)(pt0 + p) * 256 + k0 + kk];
        }
        __syncthreads();
#pragma unroll
        for (int kk = 0; kk < 32; kk++) {
            float v = ts[tid * 33 + kk];
            const float* aw = &AWT[(k0 + kk) * 24];
#pragma unroll
            for (int j = 0; j < 24; j++) acc[j] += v * aw[j];
        }
        __syncthreads();
    }

    const int pt = pt0 + tid;
    const int b = pt / N_;   // uniform per block (6400 % 256 == 0)
    const int n = pt - b * N_;

    float attn[24];
#pragma unroll
    for (int c = 0; c < C_; c++) {
        float m = fmaxf(fmaxf(acc[c * 4], acc[c * 4 + 1]),
                        fmaxf(acc[c * 4 + 2], acc[c * 4 + 3]));
        float s = 0.f;
#pragma unroll
        for (int l = 0; l < L_; l++) {
            float e = expf(acc[c * 4 + l] - m);
            attn[c * 4 + l] = e;
            s += e;
        }
        float r = 1.f / s;
#pragma unroll
        for (int l = 0; l < L_; l++) attn[c * 4 + l] *= r;
    }

    float ax = anchor[(size_t)pt * 11 + 0];
    float ay = anchor[(size_t)pt * 11 + 1];
    float az = anchor[(size_t)pt * 11 + 2];
    float wxp = (1.f / (1.f + expf(-ax))) * 102.4f - 51.2f;
    float wyp = (1.f / (1.f + expf(-ay))) * 102.4f - 51.2f;
    float wzp = (1.f / (1.f + expf(-az))) * 8.f - 5.f;

#pragma unroll
    for (int c = 0; c < C_; c++) {
        const float* P = &proj[(size_t)(b * C_ + c) * 16];
        float cx = P[0] * wxp + P[1] * wyp + P[2] * wzp + P[3];
        float cy = P[4] * wxp + P[5] * wyp + P[6] * wzp + P[7];
        float cz = P[8] * wxp + P[9] * wyp + P[10] * wzp + P[11];
        float d = fmaxf(cz, 1e-4f);
        float u = cx / d, v = cy / d;

        float x0f = floorf(u), y0f = floorf(v);
        float fx1 = u - x0f, fy1 = v - y0f;
        float fx0 = 1.f - fx1, fy0 = 1.f - fy1;

        float4 wl[4]; int bsx[4];
#pragma unroll
        for (int l = 0; l < L_; l++) {
            const int W = HWW[l], H = HWH[l];
            float ax0, ax1; int bx;
            int ix = (int)fminf(fmaxf(x0f, -2.f), (float)W);
            if (ix <= -2 || ix >= W)      { ax0 = 0.f;  ax1 = 0.f;  bx = 0; }
            else if (ix == -1)            { ax0 = fx1;  ax1 = 0.f;  bx = 0; }
            else if (ix == W - 1)         { ax0 = 0.f;  ax1 = fx0;  bx = W - 2; }
            else                          { ax0 = fx0;  ax1 = fx1;  bx = ix; }
            float ay0, ay1; int by;
            int iy = (int)fminf(fmaxf(y0f, -2.f), (float)H);
            if (iy <= -2 || iy >= H)      { ay0 = 0.f;  ay1 = 0.f;  by = 0; }
            else if (iy == -1)            { ay0 = fy1;  ay1 = 0.f;  by = 0; }
            else if (iy == H - 1)         { ay0 = 0.f;  ay1 = fy0;  by = H - 2; }
            else                          { ay0 = fy0;  ay1 = fy1;  by = iy; }

            float a = attn[c * 4 + l];
            wl[l] = make_float4(a * ay0 * ax0, a * ay0 * ax1,
                                a * ay1 * ax0, a * ay1 * ax1);
            bsx[l] = by * W + bx;
        }
        size_t mi = (size_t)(b * C_ + c) * N_ + n;
        union { uint4 u; __half2 h[4]; } q0, q1;
        q0.h[0] = __floats2half2_rn(wl[0].x, wl[0].y);
        q0.h[1] = __floats2half2_rn(wl[0].z, wl[0].w);
        q0.h[2] = __floats2half2_rn(wl[1].x, wl[1].y);
        q0.h[3] = __floats2half2_rn(wl[1].z, wl[1].w);
        q1.h[0] = __floats2half2_rn(wl[2].x, wl[2].y);
        q1.h[1] = __floats2half2_rn(wl[2].z, wl[2].w);
        q1.h[2] = __floats2half2_rn(wl[3].x, wl[3].y);
        q1.h[3] = __floats2half2_rn(wl[3].z, wl[3].w);
        meta_w[mi * 2 + 0] = q0.u;
        meta_w[mi * 2 + 1] = q1.u;
        meta_b[mi] = make_int4(bsx[0], bsx[1], bsx[2], bsx[3]);
    }
}

// ---------------------------------------------------------------------------
// Kernel 2: gather. Block = (b, cam, 4-channel slice). Stage 4 fp16 channel
// planes [pixel][4ch] into LDS (119.7 KB), then loop points: 3 vector meta
// loads -> up to 16 ds_read_b64 gathers -> one coalesced 8 B fp16 store of
// the per-cam partial (PART=true), or 4 atomicAdds into agg (fallback).
// part layout: H4[((b*C+c)*SL + slice)*N + n]  -- consecutive n = coalesced.
// ---------------------------------------------------------------------------
template<bool PART>
__global__ __launch_bounds__(1024) void gather_t(
    const float* __restrict__ f0, const float* __restrict__ f1,
    const float* __restrict__ f2, const float* __restrict__ f3,
    const uint4* __restrict__ meta_w, const int4* __restrict__ meta_b,
    H4* __restrict__ part, float* __restrict__ agg)
{
    __shared__ H4 lds4[HWT];   // 119680 B

    const int tid = threadIdx.x;
    const int bid = blockIdx.x;
    const int slice = bid & 63;          // E/4 = 64 slices
    const int c = (bid >> 6) % C_;
    const int b = bid / (64 * C_);
    const int e0 = slice * 4;

    const float* fs[4] = {f0, f1, f2, f3};

#pragma unroll
    for (int l = 0; l < L_; l++) {
        const int HW = HWH[l] * HWW[l];
        const float* s0 = fs[l] + (size_t)((b * C_ + c) * E_ + e0) * HW;
        const float* s1 = s0 + HW;
        const float* s2 = s1 + HW;
        const float* s3 = s2 + HW;
        const int half = HW >> 1;
        for (int q = tid; q < half; q += 1024) {
            int p = q * 2;
            float2 v0 = *(const float2*)(s0 + p);
            float2 v1 = *(const float2*)(s1 + p);
            float2 v2 = *(const float2*)(s2 + p);
            float2 v3 = *(const float2*)(s3 + p);
            union { uint4 u; __half2 h[4]; } pk;
            pk.h[0] = __floats2half2_rn(v0.x, v1.x);   // pixel p   ch0,ch1
            pk.h[1] = __floats2half2_rn(v2.x, v3.x);   // pixel p   ch2,ch3
            pk.h[2] = __floats2half2_rn(v0.y, v1.y);   // pixel p+1 ch0,ch1
            pk.h[3] = __floats2half2_rn(v2.y, v3.y);   // pixel p+1 ch2,ch3
            *(uint4*)&lds4[LOFF[l] + p] = pk.u;
        }
    }
    __syncthreads();

    const size_t mbase = (size_t)(b * C_ + c) * N_;
    const uint4* mwp = meta_w + mbase * 2;
    const int4* mbp = meta_b + mbase;
    H4* pout = part + ((size_t)(b * C_ + c) * SL_ + slice) * N_;
    float* aggb = agg + (size_t)b * N_ * E_ + e0;

    int n = tid;
    uint4 m0, m1; int4 px;
    {
        m0 = mwp[(size_t)n * 2];
        m1 = mwp[(size_t)n * 2 + 1];
        px = mbp[n];
    }

    while (n < N_) {
        int nn = n + 1024;
        uint4 t0, t1; int4 px2;
        if (nn < N_) {
            t0 = mwp[(size_t)nn * 2];
            t1 = mwp[(size_t)nn * 2 + 1];
            px2 = mbp[nn];
        }

        union { uint4 u; __half2 h[4]; } a0u, a1u;
        a0u.u = m0; a1u.u = m1;
        float4 ws[4];
        {
            float2 p0 = __half22float2(a0u.h[0]), p1 = __half22float2(a0u.h[1]);
            float2 p2 = __half22float2(a0u.h[2]), p3 = __half22float2(a0u.h[3]);
            ws[0] = make_float4(p0.x, p0.y, p1.x, p1.y);
            ws[1] = make_float4(p2.x, p2.y, p3.x, p3.y);
            float2 p4 = __half22float2(a1u.h[0]), p5 = __half22float2(a1u.h[1]);
            float2 p6 = __half22float2(a1u.h[2]), p7 = __half22float2(a1u.h[3]);
            ws[2] = make_float4(p4.x, p4.y, p5.x, p5.y);
            ws[3] = make_float4(p6.x, p6.y, p7.x, p7.y);
        }
        const int pxs[4] = {px.x, px.y, px.z, px.w};

        float a0 = 0.f, a1 = 0.f, a2 = 0.f, a3 = 0.f;
#pragma unroll
        for (int l = 0; l < L_; l++) {
            float4 w = ws[l];
            if (w.x != 0.f || w.y != 0.f || w.z != 0.f || w.w != 0.f) {
                const int W = HWW[l];
                const int base = LOFF[l] + pxs[l];
                H4 c00 = lds4[base];
                H4 c01 = lds4[base + 1];
                H4 c10 = lds4[base + W];
                H4 c11 = lds4[base + W + 1];
                float2 f00a = __half22float2(c00.lo), f00b = __half22float2(c00.hi);
                float2 f01a = __half22float2(c01.lo), f01b = __half22float2(c01.hi);
                float2 f10a = __half22float2(c10.lo), f10b = __half22float2(c10.hi);
                float2 f11a = __half22float2(c11.lo), f11b = __half22float2(c11.hi);
                a0 += w.x * f00a.x + w.y * f01a.x + w.z * f10a.x + w.w * f11a.x;
                a1 += w.x * f00a.y + w.y * f01a.y + w.z * f10a.y + w.w * f11a.y;
                a2 += w.x * f00b.x + w.y * f01b.x + w.z * f10b.x + w.w * f11b.x;
                a3 += w.x * f00b.y + w.y * f01b.y + w.z * f10b.y + w.w * f11b.y;
            }
        }

        if (PART) {
            H4 o;
            o.lo = __floats2half2_rn(a0, a1);
            o.hi = __floats2half2_rn(a2, a3);
            pout[n] = o;                       // coalesced 8 B store
        } else {
            if (a0 != 0.f || a1 != 0.f || a2 != 0.f || a3 != 0.f) {
                float* dst = aggb + (size_t)n * E_;
                atomicAdd(dst + 0, a0);
                atomicAdd(dst + 1, a1);
                atomicAdd(dst + 2, a2);
                atomicAdd(dst + 3, a3);
            }
        }

        n = nn;
        m0 = t0; m1 = t1; px = px2;
    }
}

// ---------------------------------------------------------------------------
// Kernel 3: fused epilogue:
//   agg = sum_c partials ; tmp = agg @ vp_w^T + vp_b + inst ;
//   out = tmp @ op_w^T + op_b
// 32 points/block, 256 threads, thread = 4p x 8e register block,
// float4 (b128) LDS reads over the k dimension.
// ---------------------------------------------------------------------------
#define PT 32
#define SAS 264   // sA row stride (floats), 16B-aligned rows
#define WSS 36    // wS row stride (floats), 16B-aligned rows

template<bool PART>
__global__ __launch_bounds__(256) void gemm_t(
    const float* __restrict__ inst,
    const float* __restrict__ vp_w, const float* __restrict__ vp_b,
    const float* __restrict__ op_w, const float* __restrict__ op_b,
    const H4* __restrict__ part, float* __restrict__ io)
{
    __shared__ __align__(16) float sA[PT * SAS];    // 33792 B
    __shared__ __align__(16) float wS[256 * WSS];   // 36864 B

    const int tid = threadIdx.x;
    const int eg = tid & 31;
    const int pg = tid >> 5;
    const int p0 = blockIdx.x * PT;

    if (PART) {
        // reduce 6 cam partials into sA
        const int p = tid & 31, sg = tid >> 5;     // 8 slice-groups
        const int b = p0 / N_;                     // tile never crosses b
        const int n = p0 - b * N_ + p;
        for (int s = sg; s < SL_; s += 8) {
            float4 a4 = make_float4(0.f, 0.f, 0.f, 0.f);
#pragma unroll
            for (int c = 0; c < C_; c++) {
                H4 v = part[((size_t)(b * C_ + c) * SL_ + s) * N_ + n];
                float2 lo = __half22float2(v.lo), hi = __half22float2(v.hi);
                a4.x += lo.x; a4.y += lo.y; a4.z += hi.x; a4.w += hi.y;
            }
            *(float4*)&sA[p * SAS + s * 4] = a4;
        }
    } else {
#pragma unroll
        for (int r = 0; r < PT; r++)
            sA[r * SAS + tid] = io[(size_t)(p0 + r) * E_ + tid];
    }
    __syncthreads();

    float acc[4][8];
#pragma unroll
    for (int j = 0; j < 4; j++)
#pragma unroll
        for (int i = 0; i < 8; i++) acc[j][i] = 0.f;

    // ---- GEMM1: tmp = agg @ vp_w^T ----
    for (int k0 = 0; k0 < 256; k0 += 32) {
        __syncthreads();
#pragma unroll
        for (int r = 0; r < 32; r++) {
            int lin = r * 256 + tid;
            int e = lin >> 5, kk = lin & 31;
            wS[e * WSS + kk] = vp_w[(size_t)e * 256 + k0 + kk];
        }
        __syncthreads();
#pragma unroll
        for (int kk = 0; kk < 32; kk += 4) {
            float4 wv4[8], av4[4];
#pragma unroll
            for (int i = 0; i < 8; i++)
                wv4[i] = *(const float4*)&wS[(eg + 32 * i) * WSS + kk];
#pragma unroll
            for (int j = 0; j < 4; j++)
                av4[j] = *(const float4*)&sA[(pg * 4 + j) * SAS + k0 + kk];
#pragma unroll
            for (int j = 0; j < 4; j++)
#pragma unroll
                for (int i = 0; i < 8; i++)
                    acc[j][i] += av4[j].x * wv4[i].x + av4[j].y * wv4[i].y
                               + av4[j].z * wv4[i].z + av4[j].w * wv4[i].w;
        }
    }

    // tmp += vp_b + inst ; store into sA (reuse); reset acc
    __syncthreads();
#pragma unroll
    for (int j = 0; j < 4; j++) {
        int p = pg * 4 + j;
#pragma unroll
        for (int i = 0; i < 8; i++) {
            int e = eg + 32 * i;
            float t = acc[j][i] + vp_b[e] + inst[(size_t)(p0 + p) * E_ + e];
            sA[p * SAS + e] = t;
            acc[j][i] = 0.f;
        }
    }

    // ---- GEMM2: out = tmp @ op_w^T ----
    for (int k0 = 0; k0 < 256; k0 += 32) {
        __syncthreads();
#pragma unroll
        for (int r = 0; r < 32; r++) {
            int lin = r * 256 + tid;
            int e = lin >> 5, kk = lin & 31;
            wS[e * WSS + kk] = op_w[(size_t)e * 256 + k0 + kk];
        }
        __syncthreads();
#pragma unroll
        for (int kk = 0; kk < 32; kk += 4) {
            float4 wv4[8], av4[4];
#pragma unroll
            for (int i = 0; i < 8; i++)
                wv4[i] = *(const float4*)&wS[(eg + 32 * i) * WSS + kk];
#pragma unroll
            for (int j = 0; j < 4; j++)
                av4[j] = *(const float4*)&sA[(pg * 4 + j) * SAS + k0 + kk];
#pragma unroll
            for (int j = 0; j < 4; j++)
#pragma unroll
                for (int i = 0; i < 8; i++)
                    acc[j][i] += av4[j].x * wv4[i].x + av4[j].y * wv4[i].y
                               + av4[j].z * wv4[i].z + av4[j].w * wv4[i].w;
        }
    }

#pragma unroll
    for (int j = 0; j < 4; j++) {
        int p = pg * 4 + j;
#pragma unroll
        for (int i = 0; i < 8; i++) {
            int e = eg + 32 * i;
            io[(size_t)(p0 + p) * E_ + e] = acc[j][i] + op_b[e];
        }
    }
}

// ---------------------------------------------------------------------------
extern "C" void kernel_launch(void* const* d_in, const int* in_sizes, int n_in,
                              void* d_out, int out_size, void* d_ws, size_t ws_size,
                              hipStream_t stream)
{
    const float* inst   = (const float*)d_in[0];
    const float* anchor = (const float*)d_in[1];
    const float* proj   = (const float*)d_in[2];
    const float* f0     = (const float*)d_in[3];
    const float* f1     = (const float*)d_in[4];
    const float* f2     = (const float*)d_in[5];
    const float* f3     = (const float*)d_in[6];
    const float* attn_w = (const float*)d_in[7];
    const float* attn_b = (const float*)d_in[8];
    const float* vp_w   = (const float*)d_in[9];
    const float* vp_b   = (const float*)d_in[10];
    const float* op_w   = (const float*)d_in[11];
    const float* op_b   = (const float*)d_in[12];
    float* out = (float*)d_out;

    // ws layout: meta_w (32 B/pt) | meta_b (16 B/pt) | partials (fp16, 39 MB)
    const size_t NPT = (size_t)B_ * C_ * N_;
    uint4* meta_w = (uint4*)d_ws;
    int4* meta_b = (int4*)((char*)d_ws + NPT * 32);
    H4* part = (H4*)((char*)d_ws + NPT * 48);
    const size_t need = NPT * 48 + (size_t)B_ * C_ * SL_ * N_ * sizeof(H4);

    prep_kernel<<<(B_ * N_) / 256, 256, 0, stream>>>(
        inst, anchor, proj, attn_w, attn_b, meta_w, meta_b);

    if (ws_size >= need) {
        gather_t<true><<<B_ * C_ * SL_, 1024, 0, stream>>>(
            f0, f1, f2, f3, meta_w, meta_b, part, out);
        gemm_t<true><<<(B_ * N_) / PT, 256, 0, stream>>>(
            inst, vp_w, vp_b, op_w, op_b, part, out);
    } else {
        hipMemsetAsync(d_out, 0, (size_t)out_size * sizeof(float), stream);
        gather_t<false><<<B_ * C_ * SL_, 1024, 0, stream>>>(
            f0, f1, f2, f3, meta_w, meta_b, part, out);
        gemm_t<false><<<(B_ * N_) / PT, 256, 0, stream>>>(
            inst, vp_w, vp_b, op_w, op_b, part, out);
    }
}

// Round 4
// 365.361 us; speedup vs baseline: 2.6675x; 1.2472x over previous
//
#include <hip/hip_runtime.h>
#include <hip/hip_fp16.h>
#include <math.h>

#define B_ 2
#define N_ 6400
#define E_ 256
#define C_ 6
#define L_ 4
#define SL_ 64   // channel slices (E/4)

// Level geometry (H, W), flattened per-channel offsets, total pixels/channel
__device__ __host__ constexpr int HWH[4] = {64, 32, 16, 8};
__device__ __host__ constexpr int HWW[4] = {176, 88, 44, 22};
__device__ __host__ constexpr int LOFF[4] = {0, 11264, 14080, 14784};
#define HWT 14960

struct __align__(8) H4 { __half2 lo, hi; };   // 4 fp16 values

typedef __attribute__((ext_vector_type(8))) _Float16 half8;
typedef __attribute__((ext_vector_type(4))) _Float16 half4;
typedef __attribute__((ext_vector_type(4))) float floatx4;

// ---------------------------------------------------------------------------
// Kernel 1: per-point prep. (unchanged from R3)
// ---------------------------------------------------------------------------
__global__ __launch_bounds__(256) void prep_kernel(
    const float* __restrict__ inst, const float* __restrict__ anchor,
    const float* __restrict__ proj, const float* __restrict__ attn_w,
    const float* __restrict__ attn_b,
    uint4* __restrict__ meta_w, int4* __restrict__ meta_b)
{
    __shared__ float AWT[256 * 24];   // attn_w transposed [k][j]
    __shared__ float ts[256 * 33];    // inst tile [point][k-chunk], padded

    const int tid = threadIdx.x;

    for (int idx = tid; idx < 24 * 256; idx += 256) {
        int j = idx >> 8, k = idx & 255;
        AWT[k * 24 + j] = attn_w[idx];
    }
    __syncthreads();

    const int pt0 = blockIdx.x * 256;

    float acc[24];
#pragma unroll
    for (int j = 0; j < 24; j++) acc[j] = attn_b[j];

    for (int k0 = 0; k0 < 256; k0 += 32) {
#pragma unroll
        for (int r = 0; r < 32; r++) {
            int lin = r * 256 + tid;
            int p = lin >> 5, kk = lin & 31;
            ts[p * 33 + kk] = inst[(size_t)(pt0 + p) * 256 + k0 + kk];
        }
        __syncthreads();
#pragma unroll
        for (int kk = 0; kk < 32; kk++) {
            float v = ts[tid * 33 + kk];
            const float* aw = &AWT[(k0 + kk) * 24];
#pragma unroll
            for (int j = 0; j < 24; j++) acc[j] += v * aw[j];
        }
        __syncthreads();
    }

    const int pt = pt0 + tid;
    const int b = pt / N_;   // uniform per block (6400 % 256 == 0)
    const int n = pt - b * N_;

    float attn[24];
#pragma unroll
    for (int c = 0; c < C_; c++) {
        float m = fmaxf(fmaxf(acc[c * 4], acc[c * 4 + 1]),
                        fmaxf(acc[c * 4 + 2], acc[c * 4 + 3]));
        float s = 0.f;
#pragma unroll
        for (int l = 0; l < L_; l++) {
            float e = expf(acc[c * 4 + l] - m);
            attn[c * 4 + l] = e;
            s += e;
        }
        float r = 1.f / s;
#pragma unroll
        for (int l = 0; l < L_; l++) attn[c * 4 + l] *= r;
    }

    float ax = anchor[(size_t)pt * 11 + 0];
    float ay = anchor[(size_t)pt * 11 + 1];
    float az = anchor[(size_t)pt * 11 + 2];
    float wxp = (1.f / (1.f + expf(-ax))) * 102.4f - 51.2f;
    float wyp = (1.f / (1.f + expf(-ay))) * 102.4f - 51.2f;
    float wzp = (1.f / (1.f + expf(-az))) * 8.f - 5.f;

#pragma unroll
    for (int c = 0; c < C_; c++) {
        const float* P = &proj[(size_t)(b * C_ + c) * 16];
        float cx = P[0] * wxp + P[1] * wyp + P[2] * wzp + P[3];
        float cy = P[4] * wxp + P[5] * wyp + P[6] * wzp + P[7];
        float cz = P[8] * wxp + P[9] * wyp + P[10] * wzp + P[11];
        float d = fmaxf(cz, 1e-4f);
        float u = cx / d, v = cy / d;

        float x0f = floorf(u), y0f = floorf(v);
        float fx1 = u - x0f, fy1 = v - y0f;
        float fx0 = 1.f - fx1, fy0 = 1.f - fy1;

        float4 wl[4]; int bsx[4];
#pragma unroll
        for (int l = 0; l < L_; l++) {
            const int W = HWW[l], H = HWH[l];
            float ax0, ax1; int bx;
            int ix = (int)fminf(fmaxf(x0f, -2.f), (float)W);
            if (ix <= -2 || ix >= W)      { ax0 = 0.f;  ax1 = 0.f;  bx = 0; }
            else if (ix == -1)            { ax0 = fx1;  ax1 = 0.f;  bx = 0; }
            else if (ix == W - 1)         { ax0 = 0.f;  ax1 = fx0;  bx = W - 2; }
            else                          { ax0 = fx0;  ax1 = fx1;  bx = ix; }
            float ay0, ay1; int by;
            int iy = (int)fminf(fmaxf(y0f, -2.f), (float)H);
            if (iy <= -2 || iy >= H)      { ay0 = 0.f;  ay1 = 0.f;  by = 0; }
            else if (iy == -1)            { ay0 = fy1;  ay1 = 0.f;  by = 0; }
            else if (iy == H - 1)         { ay0 = 0.f;  ay1 = fy0;  by = H - 2; }
            else                          { ay0 = fy0;  ay1 = fy1;  by = iy; }

            float a = attn[c * 4 + l];
            wl[l] = make_float4(a * ay0 * ax0, a * ay0 * ax1,
                                a * ay1 * ax0, a * ay1 * ax1);
            bsx[l] = by * W + bx;
        }
        size_t mi = (size_t)(b * C_ + c) * N_ + n;
        union { uint4 u; __half2 h[4]; } q0, q1;
        q0.h[0] = __floats2half2_rn(wl[0].x, wl[0].y);
        q0.h[1] = __floats2half2_rn(wl[0].z, wl[0].w);
        q0.h[2] = __floats2half2_rn(wl[1].x, wl[1].y);
        q0.h[3] = __floats2half2_rn(wl[1].z, wl[1].w);
        q1.h[0] = __floats2half2_rn(wl[2].x, wl[2].y);
        q1.h[1] = __floats2half2_rn(wl[2].z, wl[2].w);
        q1.h[2] = __floats2half2_rn(wl[3].x, wl[3].y);
        q1.h[3] = __floats2half2_rn(wl[3].z, wl[3].w);
        meta_w[mi * 2 + 0] = q0.u;
        meta_w[mi * 2 + 1] = q1.u;
        meta_b[mi] = make_int4(bsx[0], bsx[1], bsx[2], bsx[3]);
    }
}

// ---------------------------------------------------------------------------
// Kernel 2: gather (unchanged from R3).
// ---------------------------------------------------------------------------
template<bool PART>
__global__ __launch_bounds__(1024) void gather_t(
    const float* __restrict__ f0, const float* __restrict__ f1,
    const float* __restrict__ f2, const float* __restrict__ f3,
    const uint4* __restrict__ meta_w, const int4* __restrict__ meta_b,
    H4* __restrict__ part, float* __restrict__ agg)
{
    __shared__ H4 lds4[HWT];   // 119680 B

    const int tid = threadIdx.x;
    const int bid = blockIdx.x;
    const int slice = bid & 63;          // E/4 = 64 slices
    const int c = (bid >> 6) % C_;
    const int b = bid / (64 * C_);
    const int e0 = slice * 4;

    const float* fs[4] = {f0, f1, f2, f3};

#pragma unroll
    for (int l = 0; l < L_; l++) {
        const int HW = HWH[l] * HWW[l];
        const float* s0 = fs[l] + (size_t)((b * C_ + c) * E_ + e0) * HW;
        const float* s1 = s0 + HW;
        const float* s2 = s1 + HW;
        const float* s3 = s2 + HW;
        const int half = HW >> 1;
        for (int q = tid; q < half; q += 1024) {
            int p = q * 2;
            float2 v0 = *(const float2*)(s0 + p);
            float2 v1 = *(const float2*)(s1 + p);
            float2 v2 = *(const float2*)(s2 + p);
            float2 v3 = *(const float2*)(s3 + p);
            union { uint4 u; __half2 h[4]; } pk;
            pk.h[0] = __floats2half2_rn(v0.x, v1.x);   // pixel p   ch0,ch1
            pk.h[1] = __floats2half2_rn(v2.x, v3.x);   // pixel p   ch2,ch3
            pk.h[2] = __floats2half2_rn(v0.y, v1.y);   // pixel p+1 ch0,ch1
            pk.h[3] = __floats2half2_rn(v2.y, v3.y);   // pixel p+1 ch2,ch3
            *(uint4*)&lds4[LOFF[l] + p] = pk.u;
        }
    }
    __syncthreads();

    const size_t mbase = (size_t)(b * C_ + c) * N_;
    const uint4* mwp = meta_w + mbase * 2;
    const int4* mbp = meta_b + mbase;
    H4* pout = part + ((size_t)(b * C_ + c) * SL_ + slice) * N_;
    float* aggb = agg + (size_t)b * N_ * E_ + e0;

    int n = tid;
    uint4 m0, m1; int4 px;
    {
        m0 = mwp[(size_t)n * 2];
        m1 = mwp[(size_t)n * 2 + 1];
        px = mbp[n];
    }

    while (n < N_) {
        int nn = n + 1024;
        uint4 t0, t1; int4 px2;
        if (nn < N_) {
            t0 = mwp[(size_t)nn * 2];
            t1 = mwp[(size_t)nn * 2 + 1];
            px2 = mbp[nn];
        }

        union { uint4 u; __half2 h[4]; } a0u, a1u;
        a0u.u = m0; a1u.u = m1;
        float4 ws[4];
        {
            float2 p0 = __half22float2(a0u.h[0]), p1 = __half22float2(a0u.h[1]);
            float2 p2 = __half22float2(a0u.h[2]), p3 = __half22float2(a0u.h[3]);
            ws[0] = make_float4(p0.x, p0.y, p1.x, p1.y);
            ws[1] = make_float4(p2.x, p2.y, p3.x, p3.y);
            float2 p4 = __half22float2(a1u.h[0]), p5 = __half22float2(a1u.h[1]);
            float2 p6 = __half22float2(a1u.h[2]), p7 = __half22float2(a1u.h[3]);
            ws[2] = make_float4(p4.x, p4.y, p5.x, p5.y);
            ws[3] = make_float4(p6.x, p6.y, p7.x, p7.y);
        }
        const int pxs[4] = {px.x, px.y, px.z, px.w};

        float a0 = 0.f, a1 = 0.f, a2 = 0.f, a3 = 0.f;
#pragma unroll
        for (int l = 0; l < L_; l++) {
            float4 w = ws[l];
            if (w.x != 0.f || w.y != 0.f || w.z != 0.f || w.w != 0.f) {
                const int W = HWW[l];
                const int base = LOFF[l] + pxs[l];
                H4 c00 = lds4[base];
                H4 c01 = lds4[base + 1];
                H4 c10 = lds4[base + W];
                H4 c11 = lds4[base + W + 1];
                float2 f00a = __half22float2(c00.lo), f00b = __half22float2(c00.hi);
                float2 f01a = __half22float2(c01.lo), f01b = __half22float2(c01.hi);
                float2 f10a = __half22float2(c10.lo), f10b = __half22float2(c10.hi);
                float2 f11a = __half22float2(c11.lo), f11b = __half22float2(c11.hi);
                a0 += w.x * f00a.x + w.y * f01a.x + w.z * f10a.x + w.w * f11a.x;
                a1 += w.x * f00a.y + w.y * f01a.y + w.z * f10a.y + w.w * f11a.y;
                a2 += w.x * f00b.x + w.y * f01b.x + w.z * f10b.x + w.w * f11b.x;
                a3 += w.x * f00b.y + w.y * f01b.y + w.z * f10b.y + w.w * f11b.y;
            }
        }

        if (PART) {
            H4 o;
            o.lo = __floats2half2_rn(a0, a1);
            o.hi = __floats2half2_rn(a2, a3);
            pout[n] = o;                       // coalesced 8 B store
        } else {
            if (a0 != 0.f || a1 != 0.f || a2 != 0.f || a3 != 0.f) {
                float* dst = aggb + (size_t)n * E_;
                atomicAdd(dst + 0, a0);
                atomicAdd(dst + 1, a1);
                atomicAdd(dst + 2, a2);
                atomicAdd(dst + 3, a3);
            }
        }

        n = nn;
        m0 = t0; m1 = t1; px = px2;
    }
}

// ---------------------------------------------------------------------------
// Kernel 3 (main path): MFMA f16 epilogue.
//   agg = sum_c partials ; tmp = agg @ vp_w^T + vp_b + inst ;
//   out = tmp @ op_w^T + op_b
// Block = 32 points x 256 cols, 4 waves; wave = 16pt x 128col.
// mfma_f32_16x16x32_f16: A[m=lane&15][k=quad*8+j], B[k][n=lane&15] (symmetric),
// C/D col=lane&15, row=quad*4+reg.
// ---------------------------------------------------------------------------
#define SAS2 264   // sA/sT row stride (halves); 528 B -> row starts 4r%32 banks
#define WSS2 72    // wS row stride (halves); 144 B -> row starts 4r%32 banks
#define KC 64      // k-chunk

__global__ __launch_bounds__(256) void gemm_mfma(
    const float* __restrict__ inst,
    const float* __restrict__ vp_w, const float* __restrict__ vp_b,
    const float* __restrict__ op_w, const float* __restrict__ op_b,
    const H4* __restrict__ part, float* __restrict__ out)
{
    __shared__ _Float16 sA[32 * SAS2];   // 16896 B  (agg tile f16)
    __shared__ _Float16 sT[32 * SAS2];   // 16896 B  (tmp tile f16)
    __shared__ _Float16 wS[256 * WSS2];  // 36864 B  (weight k-chunk f16)

    const int tid = threadIdx.x;
    const int wave = tid >> 6;
    const int lane = tid & 63;
    const int mt = wave & 1;        // m-tile (16 points)
    const int nh = wave >> 1;       // col half (128 e)
    const int q = lane >> 4;        // quad
    const int col = lane & 15;

    const int p0 = blockIdx.x * 32;
    const int b = p0 / N_;                   // tile never crosses b
    const int nbase = p0 - b * N_;

    // ---- stage sA: reduce 6 cam partials, f32 accumulate -> f16 ----
    {
        const int p = tid & 31, sg = tid >> 5;   // 8 slice-groups
        const int n = nbase + p;
        for (int s = sg; s < SL_; s += 8) {
            float a0 = 0.f, a1 = 0.f, a2 = 0.f, a3 = 0.f;
#pragma unroll
            for (int c = 0; c < C_; c++) {
                H4 v = part[((size_t)(b * C_ + c) * SL_ + s) * N_ + n];
                float2 lo = __half22float2(v.lo), hi = __half22float2(v.hi);
                a0 += lo.x; a1 += lo.y; a2 += hi.x; a3 += hi.y;
            }
            half4 h = {(_Float16)a0, (_Float16)a1, (_Float16)a2, (_Float16)a3};
            *(half4*)&sA[p * SAS2 + s * 4] = h;
        }
    }

    floatx4 acc[8];
#pragma unroll
    for (int nt = 0; nt < 8; nt++) acc[nt] = (floatx4)(0.f);

    // ---- GEMM1: tmp = agg @ vp_w^T ----
    for (int kc = 0; kc < 256 / KC; kc++) {
        __syncthreads();
        {   // stage vp_w chunk: thread = one e-row, 64 k f32 -> f16
            const float* src = vp_w + (size_t)tid * 256 + kc * KC;
            _Float16* dst = &wS[tid * WSS2];
#pragma unroll
            for (int i = 0; i < 8; i++) {
                float4 v = *(const float4*)(src + i * 8);
                float4 u = *(const float4*)(src + i * 8 + 4);
                half8 h = {(_Float16)v.x, (_Float16)v.y, (_Float16)v.z, (_Float16)v.w,
                           (_Float16)u.x, (_Float16)u.y, (_Float16)u.z, (_Float16)u.w};
                *(half8*)(dst + i * 8) = h;
            }
        }
        __syncthreads();
#pragma unroll
        for (int ks = 0; ks < KC / 32; ks++) {
            half8 a = *(half8*)&sA[(mt * 16 + col) * SAS2 + kc * KC + ks * 32 + q * 8];
#pragma unroll
            for (int nt = 0; nt < 8; nt++) {
                half8 bf = *(half8*)&wS[(nh * 128 + nt * 16 + col) * WSS2 + ks * 32 + q * 8];
                acc[nt] = __builtin_amdgcn_mfma_f32_16x16x32_f16(a, bf, acc[nt], 0, 0, 0);
            }
        }
    }

    // ---- middle: tmp = acc + vp_b + inst -> sT (f16); reset acc ----
#pragma unroll
    for (int nt = 0; nt < 8; nt++) {
        const int e = nh * 128 + nt * 16 + col;
        const float bv = vp_b[e];
#pragma unroll
        for (int r = 0; r < 4; r++) {
            const int p = mt * 16 + q * 4 + r;
            float t = acc[nt][r] + bv + inst[(size_t)(p0 + p) * E_ + e];
            sT[p * SAS2 + e] = (_Float16)t;
        }
        acc[nt] = (floatx4)(0.f);
    }

    // ---- GEMM2: out = tmp @ op_w^T ----
    for (int kc = 0; kc < 256 / KC; kc++) {
        __syncthreads();
        {
            const float* src = op_w + (size_t)tid * 256 + kc * KC;
            _Float16* dst = &wS[tid * WSS2];
#pragma unroll
            for (int i = 0; i < 8; i++) {
                float4 v = *(const float4*)(src + i * 8);
                float4 u = *(const float4*)(src + i * 8 + 4);
                half8 h = {(_Float16)v.x, (_Float16)v.y, (_Float16)v.z, (_Float16)v.w,
                           (_Float16)u.x, (_Float16)u.y, (_Float16)u.z, (_Float16)u.w};
                *(half8*)(dst + i * 8) = h;
            }
        }
        __syncthreads();
#pragma unroll
        for (int ks = 0; ks < KC / 32; ks++) {
            half8 a = *(half8*)&sT[(mt * 16 + col) * SAS2 + kc * KC + ks * 32 + q * 8];
#pragma unroll
            for (int nt = 0; nt < 8; nt++) {
                half8 bf = *(half8*)&wS[(nh * 128 + nt * 16 + col) * WSS2 + ks * 32 + q * 8];
                acc[nt] = __builtin_amdgcn_mfma_f32_16x16x32_f16(a, bf, acc[nt], 0, 0, 0);
            }
        }
    }

    // ---- store out + op_b ----
#pragma unroll
    for (int nt = 0; nt < 8; nt++) {
        const int e = nh * 128 + nt * 16 + col;
        const float ob = op_b[e];
#pragma unroll
        for (int r = 0; r < 4; r++) {
            const int p = mt * 16 + q * 4 + r;
            out[(size_t)(p0 + p) * E_ + e] = acc[nt][r] + ob;
        }
    }
}

// ---------------------------------------------------------------------------
// Fallback VALU epilogue (atomic path, PART=false) — unchanged from R3.
// ---------------------------------------------------------------------------
#define PT 32
#define SAS 264
#define WSS 36

__global__ __launch_bounds__(256) void gemm_valu(
    const float* __restrict__ inst,
    const float* __restrict__ vp_w, const float* __restrict__ vp_b,
    const float* __restrict__ op_w, const float* __restrict__ op_b,
    float* __restrict__ io)
{
    __shared__ __align__(16) float sA[PT * SAS];
    __shared__ __align__(16) float wS[256 * WSS];

    const int tid = threadIdx.x;
    const int eg = tid & 31;
    const int pg = tid >> 5;
    const int p0 = blockIdx.x * PT;

#pragma unroll
    for (int r = 0; r < PT; r++)
        sA[r * SAS + tid] = io[(size_t)(p0 + r) * E_ + tid];
    __syncthreads();

    float acc[4][8];
#pragma unroll
    for (int j = 0; j < 4; j++)
#pragma unroll
        for (int i = 0; i < 8; i++) acc[j][i] = 0.f;

    for (int k0 = 0; k0 < 256; k0 += 32) {
        __syncthreads();
#pragma unroll
        for (int r = 0; r < 32; r++) {
            int lin = r * 256 + tid;
            int e = lin >> 5, kk = lin & 31;
            wS[e * WSS + kk] = vp_w[(size_t)e * 256 + k0 + kk];
        }
        __syncthreads();
#pragma unroll
        for (int kk = 0; kk < 32; kk += 4) {
            float4 wv4[8], av4[4];
#pragma unroll
            for (int i = 0; i < 8; i++)
                wv4[i] = *(const float4*)&wS[(eg + 32 * i) * WSS + kk];
#pragma unroll
            for (int j = 0; j < 4; j++)
                av4[j] = *(const float4*)&sA[(pg * 4 + j) * SAS + k0 + kk];
#pragma unroll
            for (int j = 0; j < 4; j++)
#pragma unroll
                for (int i = 0; i < 8; i++)
                    acc[j][i] += av4[j].x * wv4[i].x + av4[j].y * wv4[i].y
                               + av4[j].z * wv4[i].z + av4[j].w * wv4[i].w;
        }
    }

    __syncthreads();
#pragma unroll
    for (int j = 0; j < 4; j++) {
        int p = pg * 4 + j;
#pragma unroll
        for (int i = 0; i < 8; i++) {
            int e = eg + 32 * i;
            float t = acc[j][i] + vp_b[e] + inst[(size_t)(p0 + p) * E_ + e];
            sA[p * SAS + e] = t;
            acc[j][i] = 0.f;
        }
    }

    for (int k0 = 0; k0 < 256; k0 += 32) {
        __syncthreads();
#pragma unroll
        for (int r = 0; r < 32; r++) {
            int lin = r * 256 + tid;
            int e = lin >> 5, kk = lin & 31;
            wS[e * WSS + kk] = op_w[(size_t)e * 256 + k0 + kk];
        }
        __syncthreads();
#pragma unroll
        for (int kk = 0; kk < 32; kk += 4) {
            float4 wv4[8], av4[4];
#pragma unroll
            for (int i = 0; i < 8; i++)
                wv4[i] = *(const float4*)&wS[(eg + 32 * i) * WSS + kk];
#pragma unroll
            for (int j = 0; j < 4; j++)
                av4[j] = *(const float4*)&sA[(pg * 4 + j) * SAS + k0 + kk];
#pragma unroll
            for (int j = 0; j < 4; j++)
#pragma unroll
                for (int i = 0; i < 8; i++)
                    acc[j][i] += av4[j].x * wv4[i].x + av4[j].y * wv4[i].y
                               + av4[j].z * wv4[i].z + av4[j].w * wv4[i].w;
        }
    }

#pragma unroll
    for (int j = 0; j < 4; j++) {
        int p = pg * 4 + j;
#pragma unroll
        for (int i = 0; i < 8; i++) {
            int e = eg + 32 * i;
            io[(size_t)(p0 + p) * E_ + e] = acc[j][i] + op_b[e];
        }
    }
}

// ---------------------------------------------------------------------------
extern "C" void kernel_launch(void* const* d_in, const int* in_sizes, int n_in,
                              void* d_out, int out_size, void* d_ws, size_t ws_size,
                              hipStream_t stream)
{
    const float* inst   = (const float*)d_in[0];
    const float* anchor = (const float*)d_in[1];
    const float* proj   = (const float*)d_in[2];
    const float* f0     = (const float*)d_in[3];
    const float* f1     = (const float*)d_in[4];
    const float* f2     = (const float*)d_in[5];
    const float* f3     = (const float*)d_in[6];
    const float* attn_w = (const float*)d_in[7];
    const float* attn_b = (const float*)d_in[8];
    const float* vp_w   = (const float*)d_in[9];
    const float* vp_b   = (const float*)d_in[10];
    const float* op_w   = (const float*)d_in[11];
    const float* op_b   = (const float*)d_in[12];
    float* out = (float*)d_out;

    // ws layout: meta_w (32 B/pt) | meta_b (16 B/pt) | partials (fp16, 39 MB)
    const size_t NPT = (size_t)B_ * C_ * N_;
    uint4* meta_w = (uint4*)d_ws;
    int4* meta_b = (int4*)((char*)d_ws + NPT * 32);
    H4* part = (H4*)((char*)d_ws + NPT * 48);
    const size_t need = NPT * 48 + (size_t)B_ * C_ * SL_ * N_ * sizeof(H4);

    prep_kernel<<<(B_ * N_) / 256, 256, 0, stream>>>(
        inst, anchor, proj, attn_w, attn_b, meta_w, meta_b);

    if (ws_size >= need) {
        gather_t<true><<<B_ * C_ * SL_, 1024, 0, stream>>>(
            f0, f1, f2, f3, meta_w, meta_b, part, out);
        gemm_mfma<<<(B_ * N_) / 32, 256, 0, stream>>>(
            inst, vp_w, vp_b, op_w, op_b, part, out);
    } else {
        hipMemsetAsync(d_out, 0, (size_t)out_size * sizeof(float), stream);
        gather_t<false><<<B_ * C_ * SL_, 1024, 0, stream>>>(
            f0, f1, f2, f3, meta_w, meta_b, part, out);
        gemm_valu<<<(B_ * N_) / PT, 256, 0, stream>>>(
            inst, vp_w, vp_b, op_w, op_b, out);
    }
}

// Round 5
// 353.730 us; speedup vs baseline: 2.7552x; 1.0329x over previous
//
#include <hip/hip_runtime.h>
#include <hip/hip_fp16.h>
#include <math.h>

#define B_ 2
#define N_ 6400
#define E_ 256
#define C_ 6
#define L_ 4
#define SL2_ 128  // 2-channel slices (E/2)

// Level geometry (H, W), flattened per-channel offsets, total pixels/channel
__device__ __host__ constexpr int HWH[4] = {64, 32, 16, 8};
__device__ __host__ constexpr int HWW[4] = {176, 88, 44, 22};
__device__ __host__ constexpr int LOFF[4] = {0, 11264, 14080, 14784};
#define HWT 14960

struct __align__(8) H4 { __half2 lo, hi; };   // 4 fp16 values

typedef __attribute__((ext_vector_type(8))) _Float16 half8;
typedef __attribute__((ext_vector_type(4))) _Float16 half4;
typedef __attribute__((ext_vector_type(4))) float floatx4;

// ---------------------------------------------------------------------------
// Kernel 1: per-point prep. (unchanged from R4)
// ---------------------------------------------------------------------------
__global__ __launch_bounds__(256) void prep_kernel(
    const float* __restrict__ inst, const float* __restrict__ anchor,
    const float* __restrict__ proj, const float* __restrict__ attn_w,
    const float* __restrict__ attn_b,
    uint4* __restrict__ meta_w, int4* __restrict__ meta_b)
{
    __shared__ float AWT[256 * 24];   // attn_w transposed [k][j]
    __shared__ float ts[256 * 33];    // inst tile [point][k-chunk], padded

    const int tid = threadIdx.x;

    for (int idx = tid; idx < 24 * 256; idx += 256) {
        int j = idx >> 8, k = idx & 255;
        AWT[k * 24 + j] = attn_w[idx];
    }
    __syncthreads();

    const int pt0 = blockIdx.x * 256;

    float acc[24];
#pragma unroll
    for (int j = 0; j < 24; j++) acc[j] = attn_b[j];

    for (int k0 = 0; k0 < 256; k0 += 32) {
#pragma unroll
        for (int r = 0; r < 32; r++) {
            int lin = r * 256 + tid;
            int p = lin >> 5, kk = lin & 31;
            ts[p * 33 + kk] = inst[(size_t)(pt0 + p) * 256 + k0 + kk];
        }
        __syncthreads();
#pragma unroll
        for (int kk = 0; kk < 32; kk++) {
            float v = ts[tid * 33 + kk];
            const float* aw = &AWT[(k0 + kk) * 24];
#pragma unroll
            for (int j = 0; j < 24; j++) acc[j] += v * aw[j];
        }
        __syncthreads();
    }

    const int pt = pt0 + tid;
    const int b = pt / N_;   // uniform per block (6400 % 256 == 0)
    const int n = pt - b * N_;

    float attn[24];
#pragma unroll
    for (int c = 0; c < C_; c++) {
        float m = fmaxf(fmaxf(acc[c * 4], acc[c * 4 + 1]),
                        fmaxf(acc[c * 4 + 2], acc[c * 4 + 3]));
        float s = 0.f;
#pragma unroll
        for (int l = 0; l < L_; l++) {
            float e = expf(acc[c * 4 + l] - m);
            attn[c * 4 + l] = e;
            s += e;
        }
        float r = 1.f / s;
#pragma unroll
        for (int l = 0; l < L_; l++) attn[c * 4 + l] *= r;
    }

    float ax = anchor[(size_t)pt * 11 + 0];
    float ay = anchor[(size_t)pt * 11 + 1];
    float az = anchor[(size_t)pt * 11 + 2];
    float wxp = (1.f / (1.f + expf(-ax))) * 102.4f - 51.2f;
    float wyp = (1.f / (1.f + expf(-ay))) * 102.4f - 51.2f;
    float wzp = (1.f / (1.f + expf(-az))) * 8.f - 5.f;

#pragma unroll
    for (int c = 0; c < C_; c++) {
        const float* P = &proj[(size_t)(b * C_ + c) * 16];
        float cx = P[0] * wxp + P[1] * wyp + P[2] * wzp + P[3];
        float cy = P[4] * wxp + P[5] * wyp + P[6] * wzp + P[7];
        float cz = P[8] * wxp + P[9] * wyp + P[10] * wzp + P[11];
        float d = fmaxf(cz, 1e-4f);
        float u = cx / d, v = cy / d;

        float x0f = floorf(u), y0f = floorf(v);
        float fx1 = u - x0f, fy1 = v - y0f;
        float fx0 = 1.f - fx1, fy0 = 1.f - fy1;

        float4 wl[4]; int bsx[4];
#pragma unroll
        for (int l = 0; l < L_; l++) {
            const int W = HWW[l], H = HWH[l];
            float ax0, ax1; int bx;
            int ix = (int)fminf(fmaxf(x0f, -2.f), (float)W);
            if (ix <= -2 || ix >= W)      { ax0 = 0.f;  ax1 = 0.f;  bx = 0; }
            else if (ix == -1)            { ax0 = fx1;  ax1 = 0.f;  bx = 0; }
            else if (ix == W - 1)         { ax0 = 0.f;  ax1 = fx0;  bx = W - 2; }
            else                          { ax0 = fx0;  ax1 = fx1;  bx = ix; }
            float ay0, ay1; int by;
            int iy = (int)fminf(fmaxf(y0f, -2.f), (float)H);
            if (iy <= -2 || iy >= H)      { ay0 = 0.f;  ay1 = 0.f;  by = 0; }
            else if (iy == -1)            { ay0 = fy1;  ay1 = 0.f;  by = 0; }
            else if (iy == H - 1)         { ay0 = 0.f;  ay1 = fy0;  by = H - 2; }
            else                          { ay0 = fy0;  ay1 = fy1;  by = iy; }

            float a = attn[c * 4 + l];
            wl[l] = make_float4(a * ay0 * ax0, a * ay0 * ax1,
                                a * ay1 * ax0, a * ay1 * ax1);
            bsx[l] = by * W + bx;
        }
        size_t mi = (size_t)(b * C_ + c) * N_ + n;
        union { uint4 u; __half2 h[4]; } q0, q1;
        q0.h[0] = __floats2half2_rn(wl[0].x, wl[0].y);
        q0.h[1] = __floats2half2_rn(wl[0].z, wl[0].w);
        q0.h[2] = __floats2half2_rn(wl[1].x, wl[1].y);
        q0.h[3] = __floats2half2_rn(wl[1].z, wl[1].w);
        q1.h[0] = __floats2half2_rn(wl[2].x, wl[2].y);
        q1.h[1] = __floats2half2_rn(wl[2].z, wl[2].w);
        q1.h[2] = __floats2half2_rn(wl[3].x, wl[3].y);
        q1.h[3] = __floats2half2_rn(wl[3].z, wl[3].w);
        meta_w[mi * 2 + 0] = q0.u;
        meta_w[mi * 2 + 1] = q1.u;
        meta_b[mi] = make_int4(bsx[0], bsx[1], bsx[2], bsx[3]);
    }
}

// ---------------------------------------------------------------------------
// Kernel 2: gather. Block = (b, cam, 2-channel slice). Stage 2 fp16 channel
// planes [pixel][2ch] into LDS (59.84 KB -> 2 blocks/CU so staging of one
// block overlaps gather of the other), then loop points: meta loads ->
// 16 ds_read_b32 gathers -> one coalesced 4 B __half2 partial store.
// part2 layout: __half2[((b*C+c)*SL2 + slice)*N + n].
// ---------------------------------------------------------------------------
template<bool PART>
__global__ __launch_bounds__(1024) void gather_t(
    const float* __restrict__ f0, const float* __restrict__ f1,
    const float* __restrict__ f2, const float* __restrict__ f3,
    const uint4* __restrict__ meta_w, const int4* __restrict__ meta_b,
    __half2* __restrict__ part2, float* __restrict__ agg)
{
    __shared__ __half2 lds2[HWT];   // 59840 B

    const int tid = threadIdx.x;
    const int bid = blockIdx.x;
    const int slice = bid & 127;         // E/2 = 128 slices
    const int c = (bid >> 7) % C_;
    const int b = bid / (128 * C_);
    const int e0 = slice * 2;

    const float* fs[4] = {f0, f1, f2, f3};

#pragma unroll
    for (int l = 0; l < L_; l++) {
        const int HW = HWH[l] * HWW[l];
        const float* s0 = fs[l] + (size_t)((b * C_ + c) * E_ + e0) * HW;
        const float* s1 = s0 + HW;
        const int quarter = HW >> 2;
        for (int q = tid; q < quarter; q += 1024) {
            int p = q * 4;
            float4 v0 = *(const float4*)(s0 + p);
            float4 v1 = *(const float4*)(s1 + p);
            union { uint4 u; __half2 h[4]; } pk;
            pk.h[0] = __floats2half2_rn(v0.x, v1.x);
            pk.h[1] = __floats2half2_rn(v0.y, v1.y);
            pk.h[2] = __floats2half2_rn(v0.z, v1.z);
            pk.h[3] = __floats2half2_rn(v0.w, v1.w);
            *(uint4*)&lds2[LOFF[l] + p] = pk.u;
        }
    }
    __syncthreads();

    const size_t mbase = (size_t)(b * C_ + c) * N_;
    const uint4* mwp = meta_w + mbase * 2;
    const int4* mbp = meta_b + mbase;
    __half2* pout = part2 + ((size_t)(b * C_ + c) * SL2_ + slice) * N_;
    float* aggb = agg + (size_t)b * N_ * E_ + e0;

    int n = tid;
    uint4 m0, m1; int4 px;
    {
        m0 = mwp[(size_t)n * 2];
        m1 = mwp[(size_t)n * 2 + 1];
        px = mbp[n];
    }

    while (n < N_) {
        int nn = n + 1024;
        uint4 t0, t1; int4 px2;
        if (nn < N_) {
            t0 = mwp[(size_t)nn * 2];
            t1 = mwp[(size_t)nn * 2 + 1];
            px2 = mbp[nn];
        }

        union { uint4 u; __half2 h[4]; } a0u, a1u;
        a0u.u = m0; a1u.u = m1;
        float4 ws[4];
        {
            float2 p0 = __half22float2(a0u.h[0]), p1 = __half22float2(a0u.h[1]);
            float2 p2 = __half22float2(a0u.h[2]), p3 = __half22float2(a0u.h[3]);
            ws[0] = make_float4(p0.x, p0.y, p1.x, p1.y);
            ws[1] = make_float4(p2.x, p2.y, p3.x, p3.y);
            float2 p4 = __half22float2(a1u.h[0]), p5 = __half22float2(a1u.h[1]);
            float2 p6 = __half22float2(a1u.h[2]), p7 = __half22float2(a1u.h[3]);
            ws[2] = make_float4(p4.x, p4.y, p5.x, p5.y);
            ws[3] = make_float4(p6.x, p6.y, p7.x, p7.y);
        }
        const int pxs[4] = {px.x, px.y, px.z, px.w};

        float a0 = 0.f, a1 = 0.f;
#pragma unroll
        for (int l = 0; l < L_; l++) {
            float4 w = ws[l];
            if (w.x != 0.f || w.y != 0.f || w.z != 0.f || w.w != 0.f) {
                const int W = HWW[l];
                const int base = LOFF[l] + pxs[l];
                float2 f00 = __half22float2(lds2[base]);
                float2 f01 = __half22float2(lds2[base + 1]);
                float2 f10 = __half22float2(lds2[base + W]);
                float2 f11 = __half22float2(lds2[base + W + 1]);
                a0 += w.x * f00.x + w.y * f01.x + w.z * f10.x + w.w * f11.x;
                a1 += w.x * f00.y + w.y * f01.y + w.z * f10.y + w.w * f11.y;
            }
        }

        if (PART) {
            pout[n] = __floats2half2_rn(a0, a1);   // coalesced 4 B store
        } else {
            if (a0 != 0.f || a1 != 0.f) {
                float* dst = aggb + (size_t)n * E_;
                atomicAdd(dst + 0, a0);
                atomicAdd(dst + 1, a1);
            }
        }

        n = nn;
        m0 = t0; m1 = t1; px = px2;
    }
}

// ---------------------------------------------------------------------------
// Kernel 3 (main path): MFMA f16 epilogue. (R4 structure; staging reads the
// 2-channel partial layout.)
// ---------------------------------------------------------------------------
#define SAS2 264   // sA/sT row stride (halves)
#define WSS2 72    // wS row stride (halves)
#define KC 64      // k-chunk

__global__ __launch_bounds__(256) void gemm_mfma(
    const float* __restrict__ inst,
    const float* __restrict__ vp_w, const float* __restrict__ vp_b,
    const float* __restrict__ op_w, const float* __restrict__ op_b,
    const __half2* __restrict__ part2, float* __restrict__ out)
{
    __shared__ _Float16 sA[32 * SAS2];   // 16896 B
    __shared__ _Float16 sT[32 * SAS2];   // 16896 B
    __shared__ _Float16 wS[256 * WSS2];  // 36864 B

    const int tid = threadIdx.x;
    const int wave = tid >> 6;
    const int lane = tid & 63;
    const int mt = wave & 1;        // m-tile (16 points)
    const int nh = wave >> 1;       // col half (128 e)
    const int q = lane >> 4;        // quad
    const int col = lane & 15;

    const int p0 = blockIdx.x * 32;
    const int b = p0 / N_;                   // tile never crosses b
    const int nbase = p0 - b * N_;

    // ---- stage sA: reduce 6 cam partials (2-ch slices), f32 acc -> f16 ----
    {
        const int p = tid & 31, sg = tid >> 5;   // 8 slice-groups
        const int n = nbase + p;
        for (int s = sg; s < SL2_; s += 8) {
            float a0 = 0.f, a1 = 0.f;
#pragma unroll
            for (int c = 0; c < C_; c++) {
                float2 f = __half22float2(
                    part2[((size_t)(b * C_ + c) * SL2_ + s) * N_ + n]);
                a0 += f.x; a1 += f.y;
            }
            sA[p * SAS2 + s * 2 + 0] = (_Float16)a0;
            sA[p * SAS2 + s * 2 + 1] = (_Float16)a1;
        }
    }

    floatx4 acc[8];
#pragma unroll
    for (int nt = 0; nt < 8; nt++) acc[nt] = (floatx4)(0.f);

    // ---- GEMM1: tmp = agg @ vp_w^T ----
    for (int kc = 0; kc < 256 / KC; kc++) {
        __syncthreads();
        {   // stage vp_w chunk: thread = one e-row, 64 k f32 -> f16
            const float* src = vp_w + (size_t)tid * 256 + kc * KC;
            _Float16* dst = &wS[tid * WSS2];
#pragma unroll
            for (int i = 0; i < 8; i++) {
                float4 v = *(const float4*)(src + i * 8);
                float4 u = *(const float4*)(src + i * 8 + 4);
                half8 h = {(_Float16)v.x, (_Float16)v.y, (_Float16)v.z, (_Float16)v.w,
                           (_Float16)u.x, (_Float16)u.y, (_Float16)u.z, (_Float16)u.w};
                *(half8*)(dst + i * 8) = h;
            }
        }
        __syncthreads();
#pragma unroll
        for (int ks = 0; ks < KC / 32; ks++) {
            half8 a = *(half8*)&sA[(mt * 16 + col) * SAS2 + kc * KC + ks * 32 + q * 8];
#pragma unroll
            for (int nt = 0; nt < 8; nt++) {
                half8 bf = *(half8*)&wS[(nh * 128 + nt * 16 + col) * WSS2 + ks * 32 + q * 8];
                acc[nt] = __builtin_amdgcn_mfma_f32_16x16x32_f16(a, bf, acc[nt], 0, 0, 0);
            }
        }
    }

    // ---- middle: tmp = acc + vp_b + inst -> sT (f16); reset acc ----
#pragma unroll
    for (int nt = 0; nt < 8; nt++) {
        const int e = nh * 128 + nt * 16 + col;
        const float bv = vp_b[e];
#pragma unroll
        for (int r = 0; r < 4; r++) {
            const int p = mt * 16 + q * 4 + r;
            float t = acc[nt][r] + bv + inst[(size_t)(p0 + p) * E_ + e];
            sT[p * SAS2 + e] = (_Float16)t;
        }
        acc[nt] = (floatx4)(0.f);
    }

    // ---- GEMM2: out = tmp @ op_w^T ----
    for (int kc = 0; kc < 256 / KC; kc++) {
        __syncthreads();
        {
            const float* src = op_w + (size_t)tid * 256 + kc * KC;
            _Float16* dst = &wS[tid * WSS2];
#pragma unroll
            for (int i = 0; i < 8; i++) {
                float4 v = *(const float4*)(src + i * 8);
                float4 u = *(const float4*)(src + i * 8 + 4);
                half8 h = {(_Float16)v.x, (_Float16)v.y, (_Float16)v.z, (_Float16)v.w,
                           (_Float16)u.x, (_Float16)u.y, (_Float16)u.z, (_Float16)u.w};
                *(half8*)(dst + i * 8) = h;
            }
        }
        __syncthreads();
#pragma unroll
        for (int ks = 0; ks < KC / 32; ks++) {
            half8 a = *(half8*)&sT[(mt * 16 + col) * SAS2 + kc * KC + ks * 32 + q * 8];
#pragma unroll
            for (int nt = 0; nt < 8; nt++) {
                half8 bf = *(half8*)&wS[(nh * 128 + nt * 16 + col) * WSS2 + ks * 32 + q * 8];
                acc[nt] = __builtin_amdgcn_mfma_f32_16x16x32_f16(a, bf, acc[nt], 0, 0, 0);
            }
        }
    }

    // ---- store out + op_b ----
#pragma unroll
    for (int nt = 0; nt < 8; nt++) {
        const int e = nh * 128 + nt * 16 + col;
        const float ob = op_b[e];
#pragma unroll
        for (int r = 0; r < 4; r++) {
            const int p = mt * 16 + q * 4 + r;
            out[(size_t)(p0 + p) * E_ + e] = acc[nt][r] + ob;
        }
    }
}

// ---------------------------------------------------------------------------
// Fallback VALU epilogue (atomic path, PART=false).
// ---------------------------------------------------------------------------
#define PT 32
#define SAS 264
#define WSS 36

__global__ __launch_bounds__(256) void gemm_valu(
    const float* __restrict__ inst,
    const float* __restrict__ vp_w, const float* __restrict__ vp_b,
    const float* __restrict__ op_w, const float* __restrict__ op_b,
    float* __restrict__ io)
{
    __shared__ __align__(16) float sA[PT * SAS];
    __shared__ __align__(16) float wS[256 * WSS];

    const int tid = threadIdx.x;
    const int eg = tid & 31;
    const int pg = tid >> 5;
    const int p0 = blockIdx.x * PT;

#pragma unroll
    for (int r = 0; r < PT; r++)
        sA[r * SAS + tid] = io[(size_t)(p0 + r) * E_ + tid];
    __syncthreads();

    float acc[4][8];
#pragma unroll
    for (int j = 0; j < 4; j++)
#pragma unroll
        for (int i = 0; i < 8; i++) acc[j][i] = 0.f;

    for (int k0 = 0; k0 < 256; k0 += 32) {
        __syncthreads();
#pragma unroll
        for (int r = 0; r < 32; r++) {
            int lin = r * 256 + tid;
            int e = lin >> 5, kk = lin & 31;
            wS[e * WSS + kk] = vp_w[(size_t)e * 256 + k0 + kk];
        }
        __syncthreads();
#pragma unroll
        for (int kk = 0; kk < 32; kk += 4) {
            float4 wv4[8], av4[4];
#pragma unroll
            for (int i = 0; i < 8; i++)
                wv4[i] = *(const float4*)&wS[(eg + 32 * i) * WSS + kk];
#pragma unroll
            for (int j = 0; j < 4; j++)
                av4[j] = *(const float4*)&sA[(pg * 4 + j) * SAS + k0 + kk];
#pragma unroll
            for (int j = 0; j < 4; j++)
#pragma unroll
                for (int i = 0; i < 8; i++)
                    acc[j][i] += av4[j].x * wv4[i].x + av4[j].y * wv4[i].y
                               + av4[j].z * wv4[i].z + av4[j].w * wv4[i].w;
        }
    }

    __syncthreads();
#pragma unroll
    for (int j = 0; j < 4; j++) {
        int p = pg * 4 + j;
#pragma unroll
        for (int i = 0; i < 8; i++) {
            int e = eg + 32 * i;
            float t = acc[j][i] + vp_b[e] + inst[(size_t)(p0 + p) * E_ + e];
            sA[p * SAS + e] = t;
            acc[j][i] = 0.f;
        }
    }

    for (int k0 = 0; k0 < 256; k0 += 32) {
        __syncthreads();
#pragma unroll
        for (int r = 0; r < 32; r++) {
            int lin = r * 256 + tid;
            int e = lin >> 5, kk = lin & 31;
            wS[e * WSS + kk] = op_w[(size_t)e * 256 + k0 + kk];
        }
        __syncthreads();
#pragma unroll
        for (int kk = 0; kk < 32; kk += 4) {
            float4 wv4[8], av4[4];
#pragma unroll
            for (int i = 0; i < 8; i++)
                wv4[i] = *(const float4*)&wS[(eg + 32 * i) * WSS + kk];
#pragma unroll
            for (int j = 0; j < 4; j++)
                av4[j] = *(const float4*)&sA[(pg * 4 + j) * SAS + k0 + kk];
#pragma unroll
            for (int j = 0; j < 4; j++)
#pragma unroll
                for (int i = 0; i < 8; i++)
                    acc[j][i] += av4[j].x * wv4[i].x + av4[j].y * wv4[i].y
                               + av4[j].z * wv4[i].z + av4[j].w * wv4[i].w;
        }
    }

#pragma unroll
    for (int j = 0; j < 4; j++) {
        int p = pg * 4 + j;
#pragma unroll
        for (int i = 0; i < 8; i++) {
            int e = eg + 32 * i;
            io[(size_t)(p0 + p) * E_ + e] = acc[j][i] + op_b[e];
        }
    }
}

// ---------------------------------------------------------------------------
extern "C" void kernel_launch(void* const* d_in, const int* in_sizes, int n_in,
                              void* d_out, int out_size, void* d_ws, size_t ws_size,
                              hipStream_t stream)
{
    const float* inst   = (const float*)d_in[0];
    const float* anchor = (const float*)d_in[1];
    const float* proj   = (const float*)d_in[2];
    const float* f0     = (const float*)d_in[3];
    const float* f1     = (const float*)d_in[4];
    const float* f2     = (const float*)d_in[5];
    const float* f3     = (const float*)d_in[6];
    const float* attn_w = (const float*)d_in[7];
    const float* attn_b = (const float*)d_in[8];
    const float* vp_w   = (const float*)d_in[9];
    const float* vp_b   = (const float*)d_in[10];
    const float* op_w   = (const float*)d_in[11];
    const float* op_b   = (const float*)d_in[12];
    float* out = (float*)d_out;

    // ws layout: meta_w (32 B/pt) | meta_b (16 B/pt) | partials (fp16, 39 MB)
    const size_t NPT = (size_t)B_ * C_ * N_;
    uint4* meta_w = (uint4*)d_ws;
    int4* meta_b = (int4*)((char*)d_ws + NPT * 32);
    __half2* part2 = (__half2*)((char*)d_ws + NPT * 48);
    const size_t need = NPT * 48 + (size_t)B_ * C_ * SL2_ * N_ * sizeof(__half2);

    prep_kernel<<<(B_ * N_) / 256, 256, 0, stream>>>(
        inst, anchor, proj, attn_w, attn_b, meta_w, meta_b);

    if (ws_size >= need) {
        gather_t<true><<<B_ * C_ * SL2_, 1024, 0, stream>>>(
            f0, f1, f2, f3, meta_w, meta_b, part2, out);
        gemm_mfma<<<(B_ * N_) / 32, 256, 0, stream>>>(
            inst, vp_w, vp_b, op_w, op_b, part2, out);
    } else {
        hipMemsetAsync(d_out, 0, (size_t)out_size * sizeof(float), stream);
        gather_t<false><<<B_ * C_ * SL2_, 1024, 0, stream>>>(
            f0, f1, f2, f3, meta_w, meta_b, part2, out);
        gemm_valu<<<(B_ * N_) / PT, 256, 0, stream>>>(
            inst, vp_w, vp_b, op_w, op_b, out);
    }
}